// Round 16
// baseline (163.060 us; speedup 1.0000x reference)
//
#include <hip/hip_runtime.h>
#include <stdint.h>

typedef __bf16 bf16x8 __attribute__((ext_vector_type(8)));
typedef __bf16 bf16x2 __attribute__((ext_vector_type(2)));
typedef float f32x4 __attribute__((ext_vector_type(4)));
typedef float f32x16 __attribute__((ext_vector_type(16)));
typedef unsigned short ushort_t;
typedef unsigned int uint;
typedef uint uint4v __attribute__((ext_vector_type(4)));

#define SEQ    2048
#define DMODEL 1024
#define NHEAD  16
#define DKH    64
#define NBATCH 2
#define MROWS  (NBATCH*SEQ)   // 4096
#define LOG2E  1.44269504088896340736f

__device__ __forceinline__ uint pk2(float a, float b) {
  bf16x2 t; t[0] = (__bf16)a; t[1] = (__bf16)b;
  return __builtin_bit_cast(uint, t);
}
__device__ __forceinline__ ushort_t b1(float a) {
  return __builtin_bit_cast(ushort_t, (__bf16)a);
}
__device__ __forceinline__ float fexp2(float x) {
#if __has_builtin(__builtin_amdgcn_exp2f)
  return __builtin_amdgcn_exp2f(x);
#else
  return exp2f(x);
#endif
}

__device__ __forceinline__ void gload16(const void* g, void* l) {
  __builtin_amdgcn_global_load_lds(
      (const __attribute__((address_space(1))) void*)g,
      (__attribute__((address_space(3))) void*)l, 16, 0, 0);
}

__device__ __forceinline__ f32x4 mfma16(bf16x8 a, bf16x8 b, f32x4 c) {
  return __builtin_amdgcn_mfma_f32_16x16x32_bf16(a, b, c, 0, 0, 0);
}
__device__ __forceinline__ f32x16 mfma32(bf16x8 a, bf16x8 b, f32x16 c) {
  return __builtin_amdgcn_mfma_f32_32x32x16_bf16(a, b, c, 0, 0, 0);
}

// ------- fused fp32 -> bf16 convert + RoPE cos/sin table (one launch) -----
__global__ __launch_bounds__(256) void cvt_all(
    const float* __restrict__ x, const float* __restrict__ wq,
    const float* __restrict__ wk, const float* __restrict__ wv,
    const float* __restrict__ wo, const int* __restrict__ tokpos,
    uint2* __restrict__ out, float2* __restrict__ tab)
{
  int b = blockIdx.x;
  if (b >= 8192) {                            // rope table (fp64 for accuracy)
    int t = (b - 8192) * 256 + threadIdx.x;   // [0, 65536)
    int s = t >> 5, k = t & 31;
    double inv = pow(10000.0, -(double)(2 * k) / 64.0);
    double ang = (double)tokpos[s] * inv;
    tab[t] = make_float2((float)cos(ang), (float)sin(ang));
    return;
  }
  const float4* src; uint2* dst; int i;
  if (b < 4096) {
    i = b * 256 + threadIdx.x; src = (const float4*)x; dst = out;
  } else {
    int s = (b - 4096) >> 10;
    i = ((b - 4096) & 1023) * 256 + threadIdx.x;
    src = (const float4*)(s == 0 ? wq : s == 1 ? wk : s == 2 ? wv : wo);
    dst = out + (size_t)1048576 + (size_t)s * 262144;
  }
  float4 v = src[i];
  uint2 r; r.x = pk2(v.x, v.y); r.y = pk2(v.z, v.w);
  dst[i] = r;
}

// ---------------- NT GEMM 128x128 tile, BK=64, 4 waves --------------------
// Counted-vmcnt 2-slot schedule (R13) + XCD swizzle (R14) — both verified.
__global__ __launch_bounds__(256) void gemm_nt(
    const ushort_t* __restrict__ A, const ushort_t* __restrict__ W,
    const float2* __restrict__ tab,
    ushort_t* __restrict__ Qo, ushort_t* __restrict__ Ko, ushort_t* __restrict__ Vo,
    float* __restrict__ outf, int fused, int nbx)
{
  __shared__ ushort_t lA[2][128 * 64];
  __shared__ ushort_t lB[2][128 * 64];
  const int tid = threadIdx.x;
  const int lin = blockIdx.y * nbx + blockIdx.x;
  const int nwg = nbx * gridDim.y;
  const int n = (lin & 7) * (nwg >> 3) + (lin >> 3);
  const int vbx = n % nbx, vby = n / nbx;
  const int w = tid >> 6, l = tid & 63, lo = l & 15, hi = l >> 4;
  const int wr = (w >> 1) * 64, wc = (w & 1) * 64;
  const char* Ab = (const char*)A + (size_t)vby * 128 * 2048;
  const char* Bb = (const char*)W + (size_t)vbx * 128 * 2048;
  f32x4 acc[4][4] = {};

  const int o0 = w * 1024 + l * 16;
  const int r0 = o0 >> 7;
  const int us = ((o0 >> 4) & 7) ^ (r0 & 7);
  const char* ap = Ab + (size_t)r0 * 2048 + us * 16;
  const char* bp = Bb + (size_t)r0 * 2048 + us * 16;

  auto stage = [&](char* dA, char* dB, const char* aq, const char* bq) {
    #pragma unroll
    for (int i = 0; i < 4; ++i) {           // rows r0 + 32*i
      gload16(aq + i * 65536, dA + w * 1024 + i * 4096);
      gload16(bq + i * 65536, dB + w * 1024 + i * 4096);
    }
  };
  auto comp = [&](const ushort_t* lAb, const ushort_t* lBb) {
    #pragma unroll
    for (int c = 0; c < 2; ++c) {
      bf16x8 af[4], wf[4];
      #pragma unroll
      for (int m = 0; m < 4; ++m) {
        int row = wr + m * 16 + lo;
        af[m] = *(const bf16x8*)((const char*)lAb + row * 128 + ((c * 64 + hi * 16) ^ ((row & 7) << 4)));
      }
      #pragma unroll
      for (int n2 = 0; n2 < 4; ++n2) {
        int row = wc + n2 * 16 + lo;
        wf[n2] = *(const bf16x8*)((const char*)lBb + row * 128 + ((c * 64 + hi * 16) ^ ((row & 7) << 4)));
      }
      #pragma unroll
      for (int m = 0; m < 4; ++m)
        #pragma unroll
        for (int n2 = 0; n2 < 4; ++n2)
          acc[m][n2] = mfma16(af[m], wf[n2], acc[m][n2]);
    }
  };

  stage((char*)lA[0], (char*)lB[0], ap, bp); ap += 128; bp += 128;   // step 0
  #pragma unroll 1
  for (int it = 0; it < 8; ++it) {
    stage((char*)lA[1], (char*)lB[1], ap, bp); ap += 128; bp += 128; // step 2it+1
    asm volatile("s_waitcnt vmcnt(8)" ::: "memory");   // slot-0 writes landed
    __builtin_amdgcn_s_barrier();                      // publish slot 0
    asm volatile("" ::: "memory");
    comp(lA[0], lB[0]);
    __builtin_amdgcn_s_barrier();                      // release slot 0
    asm volatile("" ::: "memory");
    if (it < 7) {
      stage((char*)lA[0], (char*)lB[0], ap, bp); ap += 128; bp += 128; // step 2it+2
      asm volatile("s_waitcnt vmcnt(8)" ::: "memory"); // slot-1 writes landed
    } else {
      asm volatile("s_waitcnt vmcnt(0)" ::: "memory");
    }
    __builtin_amdgcn_s_barrier();                      // publish slot 1
    asm volatile("" ::: "memory");
    comp(lA[1], lB[1]);
    __builtin_amdgcn_s_barrier();                      // release slot 1
    asm volatile("" ::: "memory");
  }

  const int mode = fused ? (vbx >> 3) : 3;
  const int colblk = fused ? (vbx & 7) : vbx;
  const int rowbase = vby * 128 + wr + hi * 4;
  const int colbase = colblk * 128 + wc + lo;

  if (mode == 3) {
    #pragma unroll
    for (int m = 0; m < 4; ++m)
      #pragma unroll
      for (int n2 = 0; n2 < 4; ++n2) {
        int e = colbase + n2 * 16;
        #pragma unroll
        for (int r = 0; r < 4; ++r) {
          int row = rowbase + m * 16 + r;
          outf[(size_t)row * 1024 + e] = acc[m][n2][r];
        }
      }
    return;
  }
  if (mode == 2) {
    // V^T store with key-column permutation (PV B-operand = raw P regs).
    #pragma unroll
    for (int m = 0; m < 4; ++m) {
      int row0 = rowbase + m * 16;
      int b = row0 >> 11, s = row0 & 2047;
      int b2 = (s >> 2) & 3;                               // 4-block index
      int sp = (s & ~12) | ((b2 & 1) << 3) | ((b2 >> 1) << 2);  // swap blks 1<->2
      #pragma unroll
      for (int n2 = 0; n2 < 4; ++n2) {
        int e = colbase + n2 * 16;
        int h = e >> 6, dk = e & 63;
        uint2 pk;
        pk.x = pk2(acc[m][n2][0], acc[m][n2][1]);
        pk.y = pk2(acc[m][n2][2], acc[m][n2][3]);
        *(uint2*)(Vo + ((size_t)((b * NHEAD + h) * DKH + dk) * SEQ + sp)) = pk;
      }
    }
    return;
  }
  ushort_t* outb = (mode == 0) ? Qo : Ko;
  const float qscale = (mode == 0) ? (0.125f * LOG2E) : 1.0f;
  #pragma unroll
  for (int m = 0; m < 4; ++m) {
    #pragma unroll
    for (int n2 = 0; n2 < 4; ++n2) {
      int e = colbase + n2 * 16;
      int h = e >> 6, dk = e & 63, kf = dk >> 1;
      float sgn = (e & 1) ? 1.0f : -1.0f;
      #pragma unroll
      for (int r = 0; r < 4; ++r) {
        int row = rowbase + m * 16 + r;
        int s = row & 2047, b = row >> 11;
        float2 cs = tab[s * 32 + kf];
        float v = acc[m][n2][r];
        float p = __shfl_xor(v, 1, 64);
        float res = (v * cs.x + sgn * p * cs.y) * qscale;
        outb[((size_t)((b * NHEAD + h) * SEQ + s)) * DKH + dk] = b1(res);
      }
    }
  }
}

// ---------------- flash attention fwd: LDS-free main loop (L2-direct) -----
// R16: K/V fragments load straight from L2 (XCD swizzle keeps 4 heads = 2MB
// resident per XCD L2; FETCH confirmed ~algorithmic in R14). Addressing
// reproduces R11's LDS fragment bytes exactly -> identical arithmetic.
// LDS = 33KB epilogue tree only -> 4 blocks/CU; launch_bounds(256,3) caps
// VGPR at 170 -> 3 waves/SIMD (12 waves/CU, 1.5x R11 TLP).
__global__ __launch_bounds__(256, 3) void attn_fwd(
    const ushort_t* __restrict__ Qg, const ushort_t* __restrict__ Kg,
    const ushort_t* __restrict__ VTg, ushort_t* __restrict__ attn)
{
  __shared__ char lds[33792];                 // 32KB accO tree + 1KB lsum
  const int tid = threadIdx.x;                // 0..255
  const int w = tid >> 6, l = tid & 63;
  const int q31 = l & 31, hf = l >> 5;
  // XCD swizzle (R14): 1024 blocks = 8 XCDs x 128; each XCD gets 4 heads.
  const int lin = blockIdx.y * gridDim.x + blockIdx.x;
  const int n = (lin & 7) * 128 + (lin >> 3);
  const int bh = n >> 5;                      // 0..31
  const int q0 = (n & 31) * 64;               // block's 64 queries
  const char* Kb = (const char*)Kg + (size_t)bh * 2048 * 128;   // key rows, 128B
  const char* Vb = (const char*)VTg + (size_t)bh * 64 * 4096;   // d rows, 4096B

  // Q fragments: qreg[qb][c] = Q[q0+qb*32+q31][c*16 + hf*8 .. +7]
  bf16x8 qreg[2][4];
  #pragma unroll
  for (int qb = 0; qb < 2; ++qb) {
    const ushort_t* qp = Qg + ((size_t)bh * 2048 + q0 + qb * 32 + q31) * 64 + hf * 8;
    #pragma unroll
    for (int c = 0; c < 4; ++c) qreg[qb][c] = *(const bf16x8*)(qp + c * 16);
  }

  f32x16 accO[2][2] = {};                     // [qb][db], partial over wave's keys
  float lsum[2] = {0.f, 0.f};

  // per-lane global fragment bases (wave w owns keys kb0..kb0+511, 16 steps)
  const int kb0 = w * 512;
  const char* kbase = Kb + (size_t)(kb0 + q31) * 128 + hf * 16;   // + step*4096 + c*32
  const char* vbase = Vb + (size_t)q31 * 4096 + (size_t)kb0 * 2 + hf * 16;
  // vf(db,kcl,step) at vbase + db*131072 + step*64 + kcl*32

  #pragma unroll 2
  for (int step = 0; step < 16; ++step) {
    const char* kp = kbase + step * 4096;
    bf16x8 kf[4];
    #pragma unroll
    for (int c = 0; c < 4; ++c)
      kf[c] = *(const bf16x8*)(kp + c * 32);
    f32x16 s0 = {}, s1 = {};
    #pragma unroll
    for (int c = 0; c < 4; ++c) {
      s0 = mfma32(kf[c], qreg[0][c], s0);
      s1 = mfma32(kf[c], qreg[1][c], s1);
    }
    // p[r] <-> within-tile key (r&3) + 8*(r>>2) + 4*hf
    float p0[16], p1[16];
    float t0 = 0.f, t1 = 0.f;
    #pragma unroll
    for (int r = 0; r < 16; ++r) { p0[r] = fexp2(s0[r]); t0 += p0[r]; }
    #pragma unroll
    for (int r = 0; r < 16; ++r) { p1[r] = fexp2(s1[r]); t1 += p1[r]; }
    lsum[0] += t0; lsum[1] += t1;
    // PV: B-operand = P registers directly (V key-cols pre-permuted)
    const char* vp = vbase + step * 64;
    #pragma unroll
    for (int kcl = 0; kcl < 2; ++kcl) {
      const float* a0 = p0 + kcl * 8;
      const float* a1 = p1 + kcl * 8;
      uint4v u0 = { pk2(a0[0], a0[1]), pk2(a0[2], a0[3]),
                    pk2(a0[4], a0[5]), pk2(a0[6], a0[7]) };
      uint4v u1 = { pk2(a1[0], a1[1]), pk2(a1[2], a1[3]),
                    pk2(a1[4], a1[5]), pk2(a1[6], a1[7]) };
      bf16x8 pb0 = __builtin_bit_cast(bf16x8, u0);
      bf16x8 pb1 = __builtin_bit_cast(bf16x8, u1);
      bf16x8 vf0 = *(const bf16x8*)(vp + kcl * 32);            // d 0..31
      bf16x8 vf1 = *(const bf16x8*)(vp + 131072 + kcl * 32);   // d 32..63
      accO[0][0] = mfma32(vf0, pb0, accO[0][0]);
      accO[0][1] = mfma32(vf1, pb0, accO[0][1]);
      accO[1][0] = mfma32(vf0, pb1, accO[1][0]);
      accO[1][1] = mfma32(vf1, pb1, accO[1][1]);
    }
  }

  // -------- tree-combine the 4 key-quarter partials (linear softmax) ------
  // round 1: waves 2,3 dump; waves 0,1 add partner (w+2)
  if (w >= 2) {
    char* dst = lds + (w - 2) * 16384;
    #pragma unroll
    for (int qb = 0; qb < 2; ++qb)
      #pragma unroll
      for (int db = 0; db < 2; ++db)
        #pragma unroll
        for (int c2 = 0; c2 < 4; ++c2) {
          int j = qb * 8 + db * 4 + c2;
          f32x4 v = { accO[qb][db][c2 * 4 + 0], accO[qb][db][c2 * 4 + 1],
                      accO[qb][db][c2 * 4 + 2], accO[qb][db][c2 * 4 + 3] };
          *(f32x4*)(dst + j * 1024 + l * 16) = v;
        }
    *(float2*)(lds + 32768 + (w - 2) * 512 + l * 8) = make_float2(lsum[0], lsum[1]);
  }
  __syncthreads();
  if (w < 2) {
    const char* srcp = lds + w * 16384;
    #pragma unroll
    for (int qb = 0; qb < 2; ++qb)
      #pragma unroll
      for (int db = 0; db < 2; ++db)
        #pragma unroll
        for (int c2 = 0; c2 < 4; ++c2) {
          int j = qb * 8 + db * 4 + c2;
          f32x4 v = *(const f32x4*)(srcp + j * 1024 + l * 16);
          accO[qb][db][c2 * 4 + 0] += v[0];
          accO[qb][db][c2 * 4 + 1] += v[1];
          accO[qb][db][c2 * 4 + 2] += v[2];
          accO[qb][db][c2 * 4 + 3] += v[3];
        }
    float2 lo = *(const float2*)(lds + 32768 + w * 512 + l * 8);
    lsum[0] += lo.x; lsum[1] += lo.y;
  }
  __syncthreads();
  // round 2: exchange halves — wave0 writes its qb1, wave1 writes its qb0
  if (w == 0) {
    #pragma unroll
    for (int db = 0; db < 2; ++db)
      #pragma unroll
      for (int c2 = 0; c2 < 4; ++c2) {
        int j = db * 4 + c2;
        f32x4 v = { accO[1][db][c2 * 4 + 0], accO[1][db][c2 * 4 + 1],
                    accO[1][db][c2 * 4 + 2], accO[1][db][c2 * 4 + 3] };
        *(f32x4*)(lds + j * 1024 + l * 16) = v;
      }
    *(float*)(lds + 32768 + l * 4) = lsum[1];
  } else if (w == 1) {
    #pragma unroll
    for (int db = 0; db < 2; ++db)
      #pragma unroll
      for (int c2 = 0; c2 < 4; ++c2) {
        int j = db * 4 + c2;
        f32x4 v = { accO[0][db][c2 * 4 + 0], accO[0][db][c2 * 4 + 1],
                    accO[0][db][c2 * 4 + 2], accO[0][db][c2 * 4 + 3] };
        *(f32x4*)(lds + 8192 + j * 1024 + l * 16) = v;
      }
    *(float*)(lds + 32768 + 512 + l * 4) = lsum[0];
  }
  __syncthreads();
  int b = bh >> 4, head = bh & 15;
  if (w == 0) {
    // final qb0 = own qb0 + wave1's qb0; store rows q0..q0+31
    #pragma unroll
    for (int db = 0; db < 2; ++db)
      #pragma unroll
      for (int c2 = 0; c2 < 4; ++c2) {
        int j = db * 4 + c2;
        f32x4 v = *(const f32x4*)(lds + 8192 + j * 1024 + l * 16);
        accO[0][db][c2 * 4 + 0] += v[0];
        accO[0][db][c2 * 4 + 1] += v[1];
        accO[0][db][c2 * 4 + 2] += v[2];
        accO[0][db][c2 * 4 + 3] += v[3];
      }
    lsum[0] += *(const float*)(lds + 32768 + 512 + l * 4);
    float lt = lsum[0] + __shfl_xor(lsum[0], 32, 64);
    float inv = 1.0f / lt;
    ushort_t* op = attn + (size_t)(b * 2048 + q0 + q31) * 1024 + head * 64;
    #pragma unroll
    for (int db = 0; db < 2; ++db)
      #pragma unroll
      for (int m = 0; m < 4; ++m) {
        int d0 = db * 32 + m * 8 + hf * 4;
        uint2 pk;
        pk.x = pk2(accO[0][db][m * 4 + 0] * inv, accO[0][db][m * 4 + 1] * inv);
        pk.y = pk2(accO[0][db][m * 4 + 2] * inv, accO[0][db][m * 4 + 3] * inv);
        *(uint2*)(op + d0) = pk;
      }
  } else if (w == 1) {
    // final qb1 = own qb1 + wave0's qb1; store rows q0+32..q0+63
    #pragma unroll
    for (int db = 0; db < 2; ++db)
      #pragma unroll
      for (int c2 = 0; c2 < 4; ++c2) {
        int j = db * 4 + c2;
        f32x4 v = *(const f32x4*)(lds + j * 1024 + l * 16);
        accO[1][db][c2 * 4 + 0] += v[0];
        accO[1][db][c2 * 4 + 1] += v[1];
        accO[1][db][c2 * 4 + 2] += v[2];
        accO[1][db][c2 * 4 + 3] += v[3];
      }
    lsum[1] += *(const float*)(lds + 32768 + l * 4);
    float lt = lsum[1] + __shfl_xor(lsum[1], 32, 64);
    float inv = 1.0f / lt;
    ushort_t* op = attn + (size_t)(b * 2048 + q0 + 32 + q31) * 1024 + head * 64;
    #pragma unroll
    for (int db = 0; db < 2; ++db)
      #pragma unroll
      for (int m = 0; m < 4; ++m) {
        int d0 = db * 32 + m * 8 + hf * 4;
        uint2 pk;
        pk.x = pk2(accO[1][db][m * 4 + 0] * inv, accO[1][db][m * 4 + 1] * inv);
        pk.y = pk2(accO[1][db][m * 4 + 2] * inv, accO[1][db][m * 4 + 3] * inv);
        *(uint2*)(op + d0) = pk;
      }
  }
}

// ---------------- launch ----------------
extern "C" void kernel_launch(void* const* d_in, const int* in_sizes, int n_in,
                              void* d_out, int out_size, void* d_ws, size_t ws_size,
                              hipStream_t stream) {
  const float* x  = (const float*)d_in[0];
  const int* tok  = (const int*)d_in[1];
  const float* wq = (const float*)d_in[2];
  const float* wk = (const float*)d_in[3];
  const float* wv = (const float*)d_in[4];
  const float* wo = (const float*)d_in[5];
  float* out = (float*)d_out;
  char* ws = (char*)d_ws;

  size_t off = 0;
  float2* tab = (float2*)(ws + off); off += (size_t)SEQ * 32 * sizeof(float2);   // 512 KB
  ushort_t* xb  = (ushort_t*)(ws + off); off += (size_t)MROWS * DMODEL * 2;      // 8 MB
  ushort_t* wqkv = (ushort_t*)(ws + off); off += (size_t)3 * DMODEL * DMODEL * 2; // 6 MB
  ushort_t* wob = (ushort_t*)(ws + off); off += (size_t)DMODEL * DMODEL * 2;     // 2 MB
  ushort_t* Qg  = (ushort_t*)(ws + off); off += (size_t)MROWS * DMODEL * 2;      // 8 MB
  ushort_t* Kg  = (ushort_t*)(ws + off); off += (size_t)MROWS * DMODEL * 2;      // 8 MB
  ushort_t* VTg = (ushort_t*)(ws + off); off += (size_t)MROWS * DMODEL * 2;      // 8 MB
  ushort_t* attnb = xb;  // alias: xb dead after projection GEMM
  if (ws_size < off) return;

  cvt_all<<<8448, 256, 0, stream>>>(x, wq, wk, wv, wo, tok, (uint2*)xb, tab);

  gemm_nt<<<dim3(24, 32), 256, 0, stream>>>(xb, wqkv, tab, Qg, Kg, VTg, nullptr, 1, 24);

  attn_fwd<<<dim3(SEQ / 64, NBATCH * NHEAD), 256, 0, stream>>>(Qg, Kg, VTg, attnb);

  gemm_nt<<<dim3(8, 32), 256, 0, stream>>>(attnb, wob, nullptr, nullptr, nullptr, nullptr, out, 0, 8);
}

// Round 17
// 137.366 us; speedup vs baseline: 1.1870x; 1.1870x over previous
//
#include <hip/hip_runtime.h>
#include <stdint.h>

typedef __bf16 bf16x8 __attribute__((ext_vector_type(8)));
typedef __bf16 bf16x2 __attribute__((ext_vector_type(2)));
typedef float f32x4 __attribute__((ext_vector_type(4)));
typedef float f32x16 __attribute__((ext_vector_type(16)));
typedef unsigned short ushort_t;
typedef unsigned int uint;
typedef uint uint4v __attribute__((ext_vector_type(4)));

#define SEQ    2048
#define DMODEL 1024
#define NHEAD  16
#define DKH    64
#define NBATCH 2
#define MROWS  (NBATCH*SEQ)   // 4096
#define LOG2E  1.44269504088896340736f

__device__ __forceinline__ uint pk2(float a, float b) {
  bf16x2 t; t[0] = (__bf16)a; t[1] = (__bf16)b;
  return __builtin_bit_cast(uint, t);
}
__device__ __forceinline__ ushort_t b1(float a) {
  return __builtin_bit_cast(ushort_t, (__bf16)a);
}
__device__ __forceinline__ float fexp2(float x) {
#if __has_builtin(__builtin_amdgcn_exp2f)
  return __builtin_amdgcn_exp2f(x);
#else
  return exp2f(x);
#endif
}

__device__ __forceinline__ void gload16(const void* g, void* l) {
  __builtin_amdgcn_global_load_lds(
      (const __attribute__((address_space(1))) void*)g,
      (__attribute__((address_space(3))) void*)l, 16, 0, 0);
}

__device__ __forceinline__ f32x4 mfma16(bf16x8 a, bf16x8 b, f32x4 c) {
  return __builtin_amdgcn_mfma_f32_16x16x32_bf16(a, b, c, 0, 0, 0);
}
__device__ __forceinline__ f32x16 mfma32(bf16x8 a, bf16x8 b, f32x16 c) {
  return __builtin_amdgcn_mfma_f32_32x32x16_bf16(a, b, c, 0, 0, 0);
}

// ------- fused fp32 -> bf16 convert + RoPE cos/sin table (one launch) -----
__global__ __launch_bounds__(256) void cvt_all(
    const float* __restrict__ x, const float* __restrict__ wq,
    const float* __restrict__ wk, const float* __restrict__ wv,
    const float* __restrict__ wo, const int* __restrict__ tokpos,
    uint2* __restrict__ out, float2* __restrict__ tab)
{
  int b = blockIdx.x;
  if (b >= 8192) {                            // rope table (fp64 for accuracy)
    int t = (b - 8192) * 256 + threadIdx.x;   // [0, 65536)
    int s = t >> 5, k = t & 31;
    double inv = pow(10000.0, -(double)(2 * k) / 64.0);
    double ang = (double)tokpos[s] * inv;
    tab[t] = make_float2((float)cos(ang), (float)sin(ang));
    return;
  }
  const float4* src; uint2* dst; int i;
  if (b < 4096) {
    i = b * 256 + threadIdx.x; src = (const float4*)x; dst = out;
  } else {
    int s = (b - 4096) >> 10;
    i = ((b - 4096) & 1023) * 256 + threadIdx.x;
    src = (const float4*)(s == 0 ? wq : s == 1 ? wk : s == 2 ? wv : wo);
    dst = out + (size_t)1048576 + (size_t)s * 262144;
  }
  float4 v = src[i];
  uint2 r; r.x = pk2(v.x, v.y); r.y = pk2(v.z, v.w);
  dst[i] = r;
}

// ---------------- NT GEMM 128x128 tile, BK=64, 4 waves --------------------
// Counted-vmcnt 2-slot schedule (R13) + XCD swizzle (R14) — both verified.
__global__ __launch_bounds__(256) void gemm_nt(
    const ushort_t* __restrict__ A, const ushort_t* __restrict__ W,
    const float2* __restrict__ tab,
    ushort_t* __restrict__ Qo, ushort_t* __restrict__ Ko, ushort_t* __restrict__ Vo,
    float* __restrict__ outf, int fused, int nbx)
{
  __shared__ ushort_t lA[2][128 * 64];
  __shared__ ushort_t lB[2][128 * 64];
  const int tid = threadIdx.x;
  const int lin = blockIdx.y * nbx + blockIdx.x;
  const int nwg = nbx * gridDim.y;
  const int n = (lin & 7) * (nwg >> 3) + (lin >> 3);
  const int vbx = n % nbx, vby = n / nbx;
  const int w = tid >> 6, l = tid & 63, lo = l & 15, hi = l >> 4;
  const int wr = (w >> 1) * 64, wc = (w & 1) * 64;
  const char* Ab = (const char*)A + (size_t)vby * 128 * 2048;
  const char* Bb = (const char*)W + (size_t)vbx * 128 * 2048;
  f32x4 acc[4][4] = {};

  const int o0 = w * 1024 + l * 16;
  const int r0 = o0 >> 7;
  const int us = ((o0 >> 4) & 7) ^ (r0 & 7);
  const char* ap = Ab + (size_t)r0 * 2048 + us * 16;
  const char* bp = Bb + (size_t)r0 * 2048 + us * 16;

  auto stage = [&](char* dA, char* dB, const char* aq, const char* bq) {
    #pragma unroll
    for (int i = 0; i < 4; ++i) {           // rows r0 + 32*i
      gload16(aq + i * 65536, dA + w * 1024 + i * 4096);
      gload16(bq + i * 65536, dB + w * 1024 + i * 4096);
    }
  };
  auto comp = [&](const ushort_t* lAb, const ushort_t* lBb) {
    #pragma unroll
    for (int c = 0; c < 2; ++c) {
      bf16x8 af[4], wf[4];
      #pragma unroll
      for (int m = 0; m < 4; ++m) {
        int row = wr + m * 16 + lo;
        af[m] = *(const bf16x8*)((const char*)lAb + row * 128 + ((c * 64 + hi * 16) ^ ((row & 7) << 4)));
      }
      #pragma unroll
      for (int n2 = 0; n2 < 4; ++n2) {
        int row = wc + n2 * 16 + lo;
        wf[n2] = *(const bf16x8*)((const char*)lBb + row * 128 + ((c * 64 + hi * 16) ^ ((row & 7) << 4)));
      }
      #pragma unroll
      for (int m = 0; m < 4; ++m)
        #pragma unroll
        for (int n2 = 0; n2 < 4; ++n2)
          acc[m][n2] = mfma16(af[m], wf[n2], acc[m][n2]);
    }
  };

  stage((char*)lA[0], (char*)lB[0], ap, bp); ap += 128; bp += 128;   // step 0
  #pragma unroll 1
  for (int it = 0; it < 8; ++it) {
    stage((char*)lA[1], (char*)lB[1], ap, bp); ap += 128; bp += 128; // step 2it+1
    asm volatile("s_waitcnt vmcnt(8)" ::: "memory");   // slot-0 writes landed
    __builtin_amdgcn_s_barrier();                      // publish slot 0
    asm volatile("" ::: "memory");
    comp(lA[0], lB[0]);
    __builtin_amdgcn_s_barrier();                      // release slot 0
    asm volatile("" ::: "memory");
    if (it < 7) {
      stage((char*)lA[0], (char*)lB[0], ap, bp); ap += 128; bp += 128; // step 2it+2
      asm volatile("s_waitcnt vmcnt(8)" ::: "memory"); // slot-1 writes landed
    } else {
      asm volatile("s_waitcnt vmcnt(0)" ::: "memory");
    }
    __builtin_amdgcn_s_barrier();                      // publish slot 1
    asm volatile("" ::: "memory");
    comp(lA[1], lB[1]);
    __builtin_amdgcn_s_barrier();                      // release slot 1
    asm volatile("" ::: "memory");
  }

  const int mode = fused ? (vbx >> 3) : 3;
  const int colblk = fused ? (vbx & 7) : vbx;
  const int rowbase = vby * 128 + wr + hi * 4;
  const int colbase = colblk * 128 + wc + lo;

  if (mode == 3) {
    #pragma unroll
    for (int m = 0; m < 4; ++m)
      #pragma unroll
      for (int n2 = 0; n2 < 4; ++n2) {
        int e = colbase + n2 * 16;
        #pragma unroll
        for (int r = 0; r < 4; ++r) {
          int row = rowbase + m * 16 + r;
          outf[(size_t)row * 1024 + e] = acc[m][n2][r];
        }
      }
    return;
  }
  if (mode == 2) {
    // V^T store with key-column permutation (PV B-operand = raw P regs).
    #pragma unroll
    for (int m = 0; m < 4; ++m) {
      int row0 = rowbase + m * 16;
      int b = row0 >> 11, s = row0 & 2047;
      int b2 = (s >> 2) & 3;                               // 4-block index
      int sp = (s & ~12) | ((b2 & 1) << 3) | ((b2 >> 1) << 2);  // swap blks 1<->2
      #pragma unroll
      for (int n2 = 0; n2 < 4; ++n2) {
        int e = colbase + n2 * 16;
        int h = e >> 6, dk = e & 63;
        uint2 pk;
        pk.x = pk2(acc[m][n2][0], acc[m][n2][1]);
        pk.y = pk2(acc[m][n2][2], acc[m][n2][3]);
        *(uint2*)(Vo + ((size_t)((b * NHEAD + h) * DKH + dk) * SEQ + sp)) = pk;
      }
    }
    return;
  }
  ushort_t* outb = (mode == 0) ? Qo : Ko;
  const float qscale = (mode == 0) ? (0.125f * LOG2E) : 1.0f;
  #pragma unroll
  for (int m = 0; m < 4; ++m) {
    #pragma unroll
    for (int n2 = 0; n2 < 4; ++n2) {
      int e = colbase + n2 * 16;
      int h = e >> 6, dk = e & 63, kf = dk >> 1;
      float sgn = (e & 1) ? 1.0f : -1.0f;
      #pragma unroll
      for (int r = 0; r < 4; ++r) {
        int row = rowbase + m * 16 + r;
        int s = row & 2047, b = row >> 11;
        float2 cs = tab[s * 32 + kf];
        float v = acc[m][n2][r];
        float p = __shfl_xor(v, 1, 64);
        float res = (v * cs.x + sgn * p * cs.y) * qscale;
        outb[((size_t)((b * NHEAD + h) * SEQ + s)) * DKH + dk] = b1(res);
      }
    }
  }
}

// ---------------- flash attention fwd: L2-direct + register prefetch ------
// R17: R16's L2-direct addressing (verified) + explicit one-step register
// prefetch (T14 issue-early/use-late; even/odd NAMED sets per rule #20).
// load(B,t+1) -> compute(A,t) -> load(A,t+2) -> compute(B,t+1): each step's
// loads issue one full compute-step (~700cyc) before first use, covering L2
// latency (~200-400cyc). No LDS / fences / gload_lds in the main loop.
__global__ __launch_bounds__(256, 2) void attn_fwd(
    const ushort_t* __restrict__ Qg, const ushort_t* __restrict__ Kg,
    const ushort_t* __restrict__ VTg, ushort_t* __restrict__ attn)
{
  __shared__ char lds[33792];                 // 32KB accO tree + 1KB lsum
  const int tid = threadIdx.x;                // 0..255
  const int w = tid >> 6, l = tid & 63;
  const int q31 = l & 31, hf = l >> 5;
  // XCD swizzle (R14): 1024 blocks = 8 XCDs x 128; each XCD gets 4 heads.
  const int lin = blockIdx.y * gridDim.x + blockIdx.x;
  const int n = (lin & 7) * 128 + (lin >> 3);
  const int bh = n >> 5;                      // 0..31
  const int q0 = (n & 31) * 64;               // block's 64 queries
  const char* Kb = (const char*)Kg + (size_t)bh * 2048 * 128;   // key rows, 128B
  const char* Vb = (const char*)VTg + (size_t)bh * 64 * 4096;   // d rows, 4096B

  // Q fragments: qreg[qb][c] = Q[q0+qb*32+q31][c*16 + hf*8 .. +7]
  bf16x8 qreg[2][4];
  #pragma unroll
  for (int qb = 0; qb < 2; ++qb) {
    const ushort_t* qp = Qg + ((size_t)bh * 2048 + q0 + qb * 32 + q31) * 64 + hf * 8;
    #pragma unroll
    for (int c = 0; c < 4; ++c) qreg[qb][c] = *(const bf16x8*)(qp + c * 16);
  }

  f32x16 accO[2][2] = {};                     // [qb][db], partial over wave's keys
  float lsum[2] = {0.f, 0.f};

  // per-lane global fragment bases (wave w owns keys kb0..kb0+511, 16 steps)
  const int kb0 = w * 512;
  const char* kbase = Kb + (size_t)(kb0 + q31) * 128 + hf * 16;   // + step*4096 + c*32
  const char* vbase = Vb + (size_t)q31 * 4096 + (size_t)kb0 * 2 + hf * 16;
  // vf[kcl + 2*db] at vbase + step*64 + kcl*32 + db*131072

  bf16x8 kA[4], kB[4], vA[4], vB[4];          // named even/odd sets (rule #20)

  auto loadK = [&](bf16x8* kf, int step) {
    const char* kp = kbase + step * 4096;
    #pragma unroll
    for (int c = 0; c < 4; ++c) kf[c] = *(const bf16x8*)(kp + c * 32);
  };
  auto loadV = [&](bf16x8* vf, int step) {
    const char* vp = vbase + step * 64;
    vf[0] = *(const bf16x8*)(vp);
    vf[1] = *(const bf16x8*)(vp + 32);
    vf[2] = *(const bf16x8*)(vp + 131072);
    vf[3] = *(const bf16x8*)(vp + 131072 + 32);
  };
  auto computeStep = [&](const bf16x8* kf, const bf16x8* vf) {
    bf16x8 pb[2][2];
    #pragma unroll
    for (int qb = 0; qb < 2; ++qb) {
      f32x16 s = {};
      #pragma unroll
      for (int c = 0; c < 4; ++c) s = mfma32(kf[c], qreg[qb][c], s);
      // p[r] <-> within-tile key (r&3) + 8*(r>>2) + 4*hf
      float p[16];
      float ts = 0.f;
      #pragma unroll
      for (int r = 0; r < 16; ++r) { p[r] = fexp2(s[r]); ts += p[r]; }
      lsum[qb] += ts;
      #pragma unroll
      for (int kcl = 0; kcl < 2; ++kcl) {
        const float* a = p + kcl * 8;
        uint4v u = { pk2(a[0], a[1]), pk2(a[2], a[3]),
                     pk2(a[4], a[5]), pk2(a[6], a[7]) };
        pb[qb][kcl] = __builtin_bit_cast(bf16x8, u);
      }
    }
    #pragma unroll
    for (int kcl = 0; kcl < 2; ++kcl) {
      accO[0][0] = mfma32(vf[kcl],     pb[0][kcl], accO[0][0]);
      accO[0][1] = mfma32(vf[kcl + 2], pb[0][kcl], accO[0][1]);
      accO[1][0] = mfma32(vf[kcl],     pb[1][kcl], accO[1][0]);
      accO[1][1] = mfma32(vf[kcl + 2], pb[1][kcl], accO[1][1]);
    }
  };

  loadK(kA, 0); loadV(vA, 0);
  #pragma unroll 1
  for (int it = 0; it < 8; ++it) {
    const int t = it * 2;
    loadK(kB, t + 1); loadV(vB, t + 1);       // issue t+1 before compute(t)
    computeStep(kA, vA);                      // step t
    if (it < 7) { loadK(kA, t + 2); loadV(vA, t + 2); }
    computeStep(kB, vB);                      // step t+1
  }

  // -------- tree-combine the 4 key-quarter partials (linear softmax) ------
  // round 1: waves 2,3 dump; waves 0,1 add partner (w+2)
  if (w >= 2) {
    char* dst = lds + (w - 2) * 16384;
    #pragma unroll
    for (int qb = 0; qb < 2; ++qb)
      #pragma unroll
      for (int db = 0; db < 2; ++db)
        #pragma unroll
        for (int c2 = 0; c2 < 4; ++c2) {
          int j = qb * 8 + db * 4 + c2;
          f32x4 v = { accO[qb][db][c2 * 4 + 0], accO[qb][db][c2 * 4 + 1],
                      accO[qb][db][c2 * 4 + 2], accO[qb][db][c2 * 4 + 3] };
          *(f32x4*)(dst + j * 1024 + l * 16) = v;
        }
    *(float2*)(lds + 32768 + (w - 2) * 512 + l * 8) = make_float2(lsum[0], lsum[1]);
  }
  __syncthreads();
  if (w < 2) {
    const char* srcp = lds + w * 16384;
    #pragma unroll
    for (int qb = 0; qb < 2; ++qb)
      #pragma unroll
      for (int db = 0; db < 2; ++db)
        #pragma unroll
        for (int c2 = 0; c2 < 4; ++c2) {
          int j = qb * 8 + db * 4 + c2;
          f32x4 v = *(const f32x4*)(srcp + j * 1024 + l * 16);
          accO[qb][db][c2 * 4 + 0] += v[0];
          accO[qb][db][c2 * 4 + 1] += v[1];
          accO[qb][db][c2 * 4 + 2] += v[2];
          accO[qb][db][c2 * 4 + 3] += v[3];
        }
    float2 lo = *(const float2*)(lds + 32768 + w * 512 + l * 8);
    lsum[0] += lo.x; lsum[1] += lo.y;
  }
  __syncthreads();
  // round 2: exchange halves — wave0 writes its qb1, wave1 writes its qb0
  if (w == 0) {
    #pragma unroll
    for (int db = 0; db < 2; ++db)
      #pragma unroll
      for (int c2 = 0; c2 < 4; ++c2) {
        int j = db * 4 + c2;
        f32x4 v = { accO[1][db][c2 * 4 + 0], accO[1][db][c2 * 4 + 1],
                    accO[1][db][c2 * 4 + 2], accO[1][db][c2 * 4 + 3] };
        *(f32x4*)(lds + j * 1024 + l * 16) = v;
      }
    *(float*)(lds + 32768 + l * 4) = lsum[1];
  } else if (w == 1) {
    #pragma unroll
    for (int db = 0; db < 2; ++db)
      #pragma unroll
      for (int c2 = 0; c2 < 4; ++c2) {
        int j = db * 4 + c2;
        f32x4 v = { accO[0][db][c2 * 4 + 0], accO[0][db][c2 * 4 + 1],
                    accO[0][db][c2 * 4 + 2], accO[0][db][c2 * 4 + 3] };
        *(f32x4*)(lds + 8192 + j * 1024 + l * 16) = v;
      }
    *(float*)(lds + 32768 + 512 + l * 4) = lsum[0];
  }
  __syncthreads();
  int b = bh >> 4, head = bh & 15;
  if (w == 0) {
    // final qb0 = own qb0 + wave1's qb0; store rows q0..q0+31
    #pragma unroll
    for (int db = 0; db < 2; ++db)
      #pragma unroll
      for (int c2 = 0; c2 < 4; ++c2) {
        int j = db * 4 + c2;
        f32x4 v = *(const f32x4*)(lds + 8192 + j * 1024 + l * 16);
        accO[0][db][c2 * 4 + 0] += v[0];
        accO[0][db][c2 * 4 + 1] += v[1];
        accO[0][db][c2 * 4 + 2] += v[2];
        accO[0][db][c2 * 4 + 3] += v[3];
      }
    lsum[0] += *(const float*)(lds + 32768 + 512 + l * 4);
    float lt = lsum[0] + __shfl_xor(lsum[0], 32, 64);
    float inv = 1.0f / lt;
    ushort_t* op = attn + (size_t)(b * 2048 + q0 + q31) * 1024 + head * 64;
    #pragma unroll
    for (int db = 0; db < 2; ++db)
      #pragma unroll
      for (int m = 0; m < 4; ++m) {
        int d0 = db * 32 + m * 8 + hf * 4;
        uint2 pk;
        pk.x = pk2(accO[0][db][m * 4 + 0] * inv, accO[0][db][m * 4 + 1] * inv);
        pk.y = pk2(accO[0][db][m * 4 + 2] * inv, accO[0][db][m * 4 + 3] * inv);
        *(uint2*)(op + d0) = pk;
      }
  } else if (w == 1) {
    // final qb1 = own qb1 + wave0's qb1; store rows q0+32..q0+63
    #pragma unroll
    for (int db = 0; db < 2; ++db)
      #pragma unroll
      for (int c2 = 0; c2 < 4; ++c2) {
        int j = db * 4 + c2;
        f32x4 v = *(const f32x4*)(lds + j * 1024 + l * 16);
        accO[1][db][c2 * 4 + 0] += v[0];
        accO[1][db][c2 * 4 + 1] += v[1];
        accO[1][db][c2 * 4 + 2] += v[2];
        accO[1][db][c2 * 4 + 3] += v[3];
      }
    lsum[1] += *(const float*)(lds + 32768 + l * 4);
    float lt = lsum[1] + __shfl_xor(lsum[1], 32, 64);
    float inv = 1.0f / lt;
    ushort_t* op = attn + (size_t)(b * 2048 + q0 + 32 + q31) * 1024 + head * 64;
    #pragma unroll
    for (int db = 0; db < 2; ++db)
      #pragma unroll
      for (int m = 0; m < 4; ++m) {
        int d0 = db * 32 + m * 8 + hf * 4;
        uint2 pk;
        pk.x = pk2(accO[1][db][m * 4 + 0] * inv, accO[1][db][m * 4 + 1] * inv);
        pk.y = pk2(accO[1][db][m * 4 + 2] * inv, accO[1][db][m * 4 + 3] * inv);
        *(uint2*)(op + d0) = pk;
      }
  }
}

// ---------------- launch ----------------
extern "C" void kernel_launch(void* const* d_in, const int* in_sizes, int n_in,
                              void* d_out, int out_size, void* d_ws, size_t ws_size,
                              hipStream_t stream) {
  const float* x  = (const float*)d_in[0];
  const int* tok  = (const int*)d_in[1];
  const float* wq = (const float*)d_in[2];
  const float* wk = (const float*)d_in[3];
  const float* wv = (const float*)d_in[4];
  const float* wo = (const float*)d_in[5];
  float* out = (float*)d_out;
  char* ws = (char*)d_ws;

  size_t off = 0;
  float2* tab = (float2*)(ws + off); off += (size_t)SEQ * 32 * sizeof(float2);   // 512 KB
  ushort_t* xb  = (ushort_t*)(ws + off); off += (size_t)MROWS * DMODEL * 2;      // 8 MB
  ushort_t* wqkv = (ushort_t*)(ws + off); off += (size_t)3 * DMODEL * DMODEL * 2; // 6 MB
  ushort_t* wob = (ushort_t*)(ws + off); off += (size_t)DMODEL * DMODEL * 2;     // 2 MB
  ushort_t* Qg  = (ushort_t*)(ws + off); off += (size_t)MROWS * DMODEL * 2;      // 8 MB
  ushort_t* Kg  = (ushort_t*)(ws + off); off += (size_t)MROWS * DMODEL * 2;      // 8 MB
  ushort_t* VTg = (ushort_t*)(ws + off); off += (size_t)MROWS * DMODEL * 2;      // 8 MB
  ushort_t* attnb = xb;  // alias: xb dead after projection GEMM
  if (ws_size < off) return;

  cvt_all<<<8448, 256, 0, stream>>>(x, wq, wk, wv, wo, tok, (uint2*)xb, tab);

  gemm_nt<<<dim3(24, 32), 256, 0, stream>>>(xb, wqkv, tab, Qg, Kg, VTg, nullptr, 1, 24);

  attn_fwd<<<dim3(SEQ / 64, NBATCH * NHEAD), 256, 0, stream>>>(Qg, Kg, VTg, attnb);

  gemm_nt<<<dim3(8, 32), 256, 0, stream>>>(attnb, wob, nullptr, nullptr, nullptr, nullptr, out, 0, 8);
}

// Round 18
// 119.708 us; speedup vs baseline: 1.3622x; 1.1475x over previous
//
#include <hip/hip_runtime.h>
#include <stdint.h>

typedef __bf16 bf16x8 __attribute__((ext_vector_type(8)));
typedef __bf16 bf16x2 __attribute__((ext_vector_type(2)));
typedef float f32x4 __attribute__((ext_vector_type(4)));
typedef float f32x16 __attribute__((ext_vector_type(16)));
typedef unsigned short ushort_t;
typedef unsigned int uint;
typedef uint uint4v __attribute__((ext_vector_type(4)));

#define SEQ    2048
#define DMODEL 1024
#define NHEAD  16
#define DKH    64
#define NBATCH 2
#define MROWS  (NBATCH*SEQ)   // 4096
#define LOG2E  1.44269504088896340736f

__device__ __forceinline__ uint pk2(float a, float b) {
  bf16x2 t; t[0] = (__bf16)a; t[1] = (__bf16)b;
  return __builtin_bit_cast(uint, t);
}
__device__ __forceinline__ ushort_t b1(float a) {
  return __builtin_bit_cast(ushort_t, (__bf16)a);
}
__device__ __forceinline__ float fexp2(float x) {
#if __has_builtin(__builtin_amdgcn_exp2f)
  return __builtin_amdgcn_exp2f(x);
#else
  return exp2f(x);
#endif
}

__device__ __forceinline__ void gload16(const void* g, void* l) {
  __builtin_amdgcn_global_load_lds(
      (const __attribute__((address_space(1))) void*)g,
      (__attribute__((address_space(3))) void*)l, 16, 0, 0);
}

__device__ __forceinline__ f32x4 mfma16(bf16x8 a, bf16x8 b, f32x4 c) {
  return __builtin_amdgcn_mfma_f32_16x16x32_bf16(a, b, c, 0, 0, 0);
}
__device__ __forceinline__ f32x16 mfma32(bf16x8 a, bf16x8 b, f32x16 c) {
  return __builtin_amdgcn_mfma_f32_32x32x16_bf16(a, b, c, 0, 0, 0);
}

// ------- fused fp32 -> bf16 convert + RoPE cos/sin table (one launch) -----
__global__ __launch_bounds__(256) void cvt_all(
    const float* __restrict__ x, const float* __restrict__ wq,
    const float* __restrict__ wk, const float* __restrict__ wv,
    const float* __restrict__ wo, const int* __restrict__ tokpos,
    uint2* __restrict__ out, float2* __restrict__ tab)
{
  int b = blockIdx.x;
  if (b >= 8192) {                            // rope table (fp64 for accuracy)
    int t = (b - 8192) * 256 + threadIdx.x;   // [0, 65536)
    int s = t >> 5, k = t & 31;
    double inv = pow(10000.0, -(double)(2 * k) / 64.0);
    double ang = (double)tokpos[s] * inv;
    tab[t] = make_float2((float)cos(ang), (float)sin(ang));
    return;
  }
  const float4* src; uint2* dst; int i;
  if (b < 4096) {
    i = b * 256 + threadIdx.x; src = (const float4*)x; dst = out;
  } else {
    int s = (b - 4096) >> 10;
    i = ((b - 4096) & 1023) * 256 + threadIdx.x;
    src = (const float4*)(s == 0 ? wq : s == 1 ? wk : s == 2 ? wv : wo);
    dst = out + (size_t)1048576 + (size_t)s * 262144;
  }
  float4 v = src[i];
  uint2 r; r.x = pk2(v.x, v.y); r.y = pk2(v.z, v.w);
  dst[i] = r;
}

// ---------------- NT GEMM 128x128 tile, BK=64, 4 waves --------------------
// Counted-vmcnt 2-slot schedule (R13) + XCD swizzle (R14) — both verified.
__global__ __launch_bounds__(256) void gemm_nt(
    const ushort_t* __restrict__ A, const ushort_t* __restrict__ W,
    const float2* __restrict__ tab,
    ushort_t* __restrict__ Qo, ushort_t* __restrict__ Ko, ushort_t* __restrict__ Vo,
    float* __restrict__ outf, int fused, int nbx)
{
  __shared__ ushort_t lA[2][128 * 64];
  __shared__ ushort_t lB[2][128 * 64];
  const int tid = threadIdx.x;
  const int lin = blockIdx.y * nbx + blockIdx.x;
  const int nwg = nbx * gridDim.y;
  const int n = (lin & 7) * (nwg >> 3) + (lin >> 3);
  const int vbx = n % nbx, vby = n / nbx;
  const int w = tid >> 6, l = tid & 63, lo = l & 15, hi = l >> 4;
  const int wr = (w >> 1) * 64, wc = (w & 1) * 64;
  const char* Ab = (const char*)A + (size_t)vby * 128 * 2048;
  const char* Bb = (const char*)W + (size_t)vbx * 128 * 2048;
  f32x4 acc[4][4] = {};

  const int o0 = w * 1024 + l * 16;
  const int r0 = o0 >> 7;
  const int us = ((o0 >> 4) & 7) ^ (r0 & 7);
  const char* ap = Ab + (size_t)r0 * 2048 + us * 16;
  const char* bp = Bb + (size_t)r0 * 2048 + us * 16;

  auto stage = [&](char* dA, char* dB, const char* aq, const char* bq) {
    #pragma unroll
    for (int i = 0; i < 4; ++i) {           // rows r0 + 32*i
      gload16(aq + i * 65536, dA + w * 1024 + i * 4096);
      gload16(bq + i * 65536, dB + w * 1024 + i * 4096);
    }
  };
  auto comp = [&](const ushort_t* lAb, const ushort_t* lBb) {
    #pragma unroll
    for (int c = 0; c < 2; ++c) {
      bf16x8 af[4], wf[4];
      #pragma unroll
      for (int m = 0; m < 4; ++m) {
        int row = wr + m * 16 + lo;
        af[m] = *(const bf16x8*)((const char*)lAb + row * 128 + ((c * 64 + hi * 16) ^ ((row & 7) << 4)));
      }
      #pragma unroll
      for (int n2 = 0; n2 < 4; ++n2) {
        int row = wc + n2 * 16 + lo;
        wf[n2] = *(const bf16x8*)((const char*)lBb + row * 128 + ((c * 64 + hi * 16) ^ ((row & 7) << 4)));
      }
      #pragma unroll
      for (int m = 0; m < 4; ++m)
        #pragma unroll
        for (int n2 = 0; n2 < 4; ++n2)
          acc[m][n2] = mfma16(af[m], wf[n2], acc[m][n2]);
    }
  };

  stage((char*)lA[0], (char*)lB[0], ap, bp); ap += 128; bp += 128;   // step 0
  #pragma unroll 1
  for (int it = 0; it < 8; ++it) {
    stage((char*)lA[1], (char*)lB[1], ap, bp); ap += 128; bp += 128; // step 2it+1
    asm volatile("s_waitcnt vmcnt(8)" ::: "memory");   // slot-0 writes landed
    __builtin_amdgcn_s_barrier();                      // publish slot 0
    asm volatile("" ::: "memory");
    comp(lA[0], lB[0]);
    __builtin_amdgcn_s_barrier();                      // release slot 0
    asm volatile("" ::: "memory");
    if (it < 7) {
      stage((char*)lA[0], (char*)lB[0], ap, bp); ap += 128; bp += 128; // step 2it+2
      asm volatile("s_waitcnt vmcnt(8)" ::: "memory"); // slot-1 writes landed
    } else {
      asm volatile("s_waitcnt vmcnt(0)" ::: "memory");
    }
    __builtin_amdgcn_s_barrier();                      // publish slot 1
    asm volatile("" ::: "memory");
    comp(lA[1], lB[1]);
    __builtin_amdgcn_s_barrier();                      // release slot 1
    asm volatile("" ::: "memory");
  }

  const int mode = fused ? (vbx >> 3) : 3;
  const int colblk = fused ? (vbx & 7) : vbx;
  const int rowbase = vby * 128 + wr + hi * 4;
  const int colbase = colblk * 128 + wc + lo;

  if (mode == 3) {
    #pragma unroll
    for (int m = 0; m < 4; ++m)
      #pragma unroll
      for (int n2 = 0; n2 < 4; ++n2) {
        int e = colbase + n2 * 16;
        #pragma unroll
        for (int r = 0; r < 4; ++r) {
          int row = rowbase + m * 16 + r;
          outf[(size_t)row * 1024 + e] = acc[m][n2][r];
        }
      }
    return;
  }
  if (mode == 2) {
    // V^T store with key-column permutation (PV B-operand = raw P regs).
    #pragma unroll
    for (int m = 0; m < 4; ++m) {
      int row0 = rowbase + m * 16;
      int b = row0 >> 11, s = row0 & 2047;
      int b2 = (s >> 2) & 3;                               // 4-block index
      int sp = (s & ~12) | ((b2 & 1) << 3) | ((b2 >> 1) << 2);  // swap blks 1<->2
      #pragma unroll
      for (int n2 = 0; n2 < 4; ++n2) {
        int e = colbase + n2 * 16;
        int h = e >> 6, dk = e & 63;
        uint2 pk;
        pk.x = pk2(acc[m][n2][0], acc[m][n2][1]);
        pk.y = pk2(acc[m][n2][2], acc[m][n2][3]);
        *(uint2*)(Vo + ((size_t)((b * NHEAD + h) * DKH + dk) * SEQ + sp)) = pk;
      }
    }
    return;
  }
  ushort_t* outb = (mode == 0) ? Qo : Ko;
  const float qscale = (mode == 0) ? (0.125f * LOG2E) : 1.0f;
  #pragma unroll
  for (int m = 0; m < 4; ++m) {
    #pragma unroll
    for (int n2 = 0; n2 < 4; ++n2) {
      int e = colbase + n2 * 16;
      int h = e >> 6, dk = e & 63, kf = dk >> 1;
      float sgn = (e & 1) ? 1.0f : -1.0f;
      #pragma unroll
      for (int r = 0; r < 4; ++r) {
        int row = rowbase + m * 16 + r;
        int s = row & 2047, b = row >> 11;
        float2 cs = tab[s * 32 + kf];
        float v = acc[m][n2][r];
        float p = __shfl_xor(v, 1, 64);
        float res = (v * cs.x + sgn * p * cs.y) * qscale;
        outb[((size_t)((b * NHEAD + h) * SEQ + s)) * DKH + dk] = b1(res);
      }
    }
  }
}

// ---------------- flash attention fwd: barrier-free per-wave pipeline -----
// R11 core + R14 XCD swizzle (verified 53.4us). R18: T5 s_setprio(1) around
// the two MFMA clusters — our waves drift freely (no barriers), the regime
// where setprio measured +4-7% (m191); GEMMs stay untouched (lockstep null).
__global__ __launch_bounds__(256) void attn_fwd(
    const ushort_t* __restrict__ Qg, const ushort_t* __restrict__ Kg,
    const ushort_t* __restrict__ VTg, ushort_t* __restrict__ attn)
{
  // main loop: wave w owns [w*16384, w*16384+16384): 2 slots of 8KB [K 4K|V 4K]
  // epilogue: accO dump 4 x 16KB at 0..65536, lsum at 65536 + w*512
  __shared__ char lds[67584];
  const int tid = threadIdx.x;                // 0..255
  const int w = tid >> 6, l = tid & 63;
  const int q31 = l & 31, hf = l >> 5, s7 = l & 7;
  // XCD swizzle (R14): 1024 blocks = 8 XCDs x 128; each XCD gets 4 heads.
  const int lin = blockIdx.y * gridDim.x + blockIdx.x;
  const int n = (lin & 7) * 128 + (lin >> 3);
  const int bh = n >> 5;                      // 0..31
  const int q0 = (n & 31) * 64;               // block's 64 queries
  const char* Kb = (const char*)Kg + (size_t)bh * 2048 * 128;   // key rows, 128B
  const char* Vb = (const char*)VTg + (size_t)bh * 64 * 4096;   // d rows, 4096B

  // Q fragments: qreg[qb][c] = Q[q0+qb*32+q31][c*16 + hf*8 .. +7]
  bf16x8 qreg[2][4];
  #pragma unroll
  for (int qb = 0; qb < 2; ++qb) {
    const ushort_t* qp = Qg + ((size_t)bh * 2048 + q0 + qb * 32 + q31) * 64 + hf * 8;
    #pragma unroll
    for (int c = 0; c < 4; ++c) qreg[qb][c] = *(const bf16x8*)(qp + c * 16);
  }

  f32x16 accO[2][2] = {};                     // [qb][db], partial over wave's keys
  float lsum[2] = {0.f, 0.f};

  // per-wave LDS read addresses (row l&31, swizzled 32B col chunks)
  char* wlds = lds + w * 16384;
  const char* ra[4];
  #pragma unroll
  for (int c = 0; c < 4; ++c)
    ra[c] = wlds + q31 * 128 + ((c * 32 + hf * 16) ^ (s7 << 4));

  // per-lane staging sources (pre-inverse-swizzled for linear LDS dest)
  const int usw = (l & 7) ^ (l >> 3);         // swizzled 16B slot for this lane
  const int kb0 = w * 512;                    // wave's key base
  const char* kst = Kb + (size_t)(kb0 + (l >> 3)) * 128 + usw * 16;          // += 4096/step
  const char* vst = Vb + (size_t)((l >> 3) + (usw >> 2) * 32) * 4096
                       + (size_t)kb0 * 2 + (usw & 3) * 16;                   // += 64/step

  auto stageT = [&](int slot) {               // 8 gload16/wave: K 4KB + V 4KB
    char* sp = wlds + slot;
    #pragma unroll
    for (int i = 0; i < 4; ++i)
      gload16(kst + i * 1024, sp + i * 1024 + l * 16);          // K rows +8i
    #pragma unroll
    for (int i = 0; i < 4; ++i)
      gload16(vst + i * 32768, sp + 4096 + i * 1024 + l * 16);  // V d-rows +8i
    kst += 4096; vst += 64;
  };

  auto tileC = [&](int slot) {                // one 32-key tile
    const int bo = slot;
    bf16x8 kf[4];
    #pragma unroll
    for (int c = 0; c < 4; ++c)
      kf[c] = *(const bf16x8*)(ra[c] + bo);
    f32x16 s0 = {}, s1 = {};
    __builtin_amdgcn_s_setprio(1);            // T5: favor MFMA wave (QK)
    #pragma unroll
    for (int c = 0; c < 4; ++c) {
      s0 = mfma32(kf[c], qreg[0][c], s0);
      s1 = mfma32(kf[c], qreg[1][c], s1);
    }
    __builtin_amdgcn_s_setprio(0);
    // p[r] <-> within-tile key (r&3) + 8*(r>>2) + 4*hf
    float p0[16], p1[16];
    float t0 = 0.f, t1 = 0.f;
    #pragma unroll
    for (int r = 0; r < 16; ++r) { p0[r] = fexp2(s0[r]); t0 += p0[r]; }
    #pragma unroll
    for (int r = 0; r < 16; ++r) { p1[r] = fexp2(s1[r]); t1 += p1[r]; }
    lsum[0] += t0; lsum[1] += t1;
    // PV: B-operand = P registers directly (V key-cols pre-permuted)
    #pragma unroll
    for (int kcl = 0; kcl < 2; ++kcl) {
      const float* a0 = p0 + kcl * 8;
      const float* a1 = p1 + kcl * 8;
      uint4v u0 = { pk2(a0[0], a0[1]), pk2(a0[2], a0[3]),
                    pk2(a0[4], a0[5]), pk2(a0[6], a0[7]) };
      uint4v u1 = { pk2(a1[0], a1[1]), pk2(a1[2], a1[3]),
                    pk2(a1[4], a1[5]), pk2(a1[6], a1[7]) };
      bf16x8 pb0 = __builtin_bit_cast(bf16x8, u0);
      bf16x8 pb1 = __builtin_bit_cast(bf16x8, u1);
      bf16x8 vf0 = *(const bf16x8*)(ra[kcl]     + bo + 4096);   // d 0..31
      bf16x8 vf1 = *(const bf16x8*)(ra[kcl + 2] + bo + 4096);   // d 32..63
      __builtin_amdgcn_s_setprio(1);          // T5: favor MFMA wave (PV)
      accO[0][0] = mfma32(vf0, pb0, accO[0][0]);
      accO[0][1] = mfma32(vf1, pb0, accO[0][1]);
      accO[1][0] = mfma32(vf0, pb1, accO[1][0]);
      accO[1][1] = mfma32(vf1, pb1, accO[1][1]);
      __builtin_amdgcn_s_setprio(0);
    }
  };

  // 16 steps, per-wave dbuf, counted vmcnt — no cross-wave barriers.
  // lgkmcnt(0) before each overwriting stage: ds_reads of the slot have
  // RETURNED before new global_load_lds to it are issued (WAR-safe, R11).
  stageT(0);                                  // step 0 -> slot 0
  #pragma unroll 1
  for (int it = 0; it < 7; ++it) {            // steps 0..13
    asm volatile("s_waitcnt lgkmcnt(0)" ::: "memory");  // slot-1 reads done (prev iter)
    stageT(8192);
    asm volatile("s_waitcnt vmcnt(8)" ::: "memory");
    __builtin_amdgcn_sched_barrier(0);
    tileC(0);
    asm volatile("s_waitcnt lgkmcnt(0)" ::: "memory");  // slot-0 reads done
    stageT(0);
    asm volatile("s_waitcnt vmcnt(8)" ::: "memory");
    __builtin_amdgcn_sched_barrier(0);
    tileC(8192);
  }
  asm volatile("s_waitcnt lgkmcnt(0)" ::: "memory");    // slot-1 reads done
  stageT(8192);                               // step 15's data
  asm volatile("s_waitcnt vmcnt(8)" ::: "memory");
  __builtin_amdgcn_sched_barrier(0);
  tileC(0);                                   // step 14
  asm volatile("s_waitcnt vmcnt(0)" ::: "memory");
  __builtin_amdgcn_sched_barrier(0);
  tileC(8192);                                // step 15

  // -------- combine the 4 key-quarter partials (linear) --------
  __syncthreads();                            // all waves done with slots
  #pragma unroll
  for (int qb = 0; qb < 2; ++qb)
    #pragma unroll
    for (int db = 0; db < 2; ++db)
      #pragma unroll
      for (int c2 = 0; c2 < 4; ++c2) {
        int j = qb * 8 + db * 4 + c2;
        f32x4 v = { accO[qb][db][c2 * 4 + 0], accO[qb][db][c2 * 4 + 1],
                    accO[qb][db][c2 * 4 + 2], accO[qb][db][c2 * 4 + 3] };
        *(f32x4*)(lds + w * 16384 + j * 1024 + l * 16) = v;
      }
  *(float2*)(lds + 65536 + w * 512 + l * 8) = make_float2(lsum[0], lsum[1]);
  __syncthreads();

  // wave w reduces j-chunks w*4..w*4+3 across all 4 wave partials
  float lt0 = 0.f, lt1 = 0.f;
  #pragma unroll
  for (int wp = 0; wp < 4; ++wp) {
    float2 lo = *(const float2*)(lds + 65536 + wp * 512 + l * 8);
    lt0 += lo.x; lt1 += lo.y;
  }
  lt0 += __shfl_xor(lt0, 32, 64);
  lt1 += __shfl_xor(lt1, 32, 64);
  float inv0 = 1.0f / lt0, inv1 = 1.0f / lt1;
  int b = bh >> 4, head = bh & 15;
  #pragma unroll
  for (int jj = 0; jj < 4; ++jj) {
    int j = w * 4 + jj;
    int qb = j >> 3, db = (j >> 2) & 1, c2 = j & 3;
    f32x4 v = {0.f, 0.f, 0.f, 0.f};
    #pragma unroll
    for (int wp = 0; wp < 4; ++wp) {
      f32x4 u = *(const f32x4*)(lds + wp * 16384 + j * 1024 + l * 16);
      v[0] += u[0]; v[1] += u[1]; v[2] += u[2]; v[3] += u[3];
    }
    float inv = qb ? inv1 : inv0;
    int d0 = db * 32 + c2 * 8 + hf * 4;
    ushort_t* op = attn + (size_t)(b * 2048 + q0 + qb * 32 + q31) * 1024 + head * 64;
    uint2 pk;
    pk.x = pk2(v[0] * inv, v[1] * inv);
    pk.y = pk2(v[2] * inv, v[3] * inv);
    *(uint2*)(op + d0) = pk;
  }
}

// ---------------- launch ----------------
extern "C" void kernel_launch(void* const* d_in, const int* in_sizes, int n_in,
                              void* d_out, int out_size, void* d_ws, size_t ws_size,
                              hipStream_t stream) {
  const float* x  = (const float*)d_in[0];
  const int* tok  = (const int*)d_in[1];
  const float* wq = (const float*)d_in[2];
  const float* wk = (const float*)d_in[3];
  const float* wv = (const float*)d_in[4];
  const float* wo = (const float*)d_in[5];
  float* out = (float*)d_out;
  char* ws = (char*)d_ws;

  size_t off = 0;
  float2* tab = (float2*)(ws + off); off += (size_t)SEQ * 32 * sizeof(float2);   // 512 KB
  ushort_t* xb  = (ushort_t*)(ws + off); off += (size_t)MROWS * DMODEL * 2;      // 8 MB
  ushort_t* wqkv = (ushort_t*)(ws + off); off += (size_t)3 * DMODEL * DMODEL * 2; // 6 MB
  ushort_t* wob = (ushort_t*)(ws + off); off += (size_t)DMODEL * DMODEL * 2;     // 2 MB
  ushort_t* Qg  = (ushort_t*)(ws + off); off += (size_t)MROWS * DMODEL * 2;      // 8 MB
  ushort_t* Kg  = (ushort_t*)(ws + off); off += (size_t)MROWS * DMODEL * 2;      // 8 MB
  ushort_t* VTg = (ushort_t*)(ws + off); off += (size_t)MROWS * DMODEL * 2;      // 8 MB
  ushort_t* attnb = xb;  // alias: xb dead after projection GEMM
  if (ws_size < off) return;

  cvt_all<<<8448, 256, 0, stream>>>(x, wq, wk, wv, wo, tok, (uint2*)xb, tab);

  gemm_nt<<<dim3(24, 32), 256, 0, stream>>>(xb, wqkv, tab, Qg, Kg, VTg, nullptr, 1, 24);

  attn_fwd<<<dim3(SEQ / 64, NBATCH * NHEAD), 256, 0, stream>>>(Qg, Kg, VTg, attnb);

  gemm_nt<<<dim3(8, 32), 256, 0, stream>>>(attnb, wob, nullptr, nullptr, nullptr, nullptr, out, 0, 8);
}

// Round 19
// 119.453 us; speedup vs baseline: 1.3651x; 1.0021x over previous
//
#include <hip/hip_runtime.h>
#include <stdint.h>

typedef __bf16 bf16x8 __attribute__((ext_vector_type(8)));
typedef __bf16 bf16x2 __attribute__((ext_vector_type(2)));
typedef float f32x4 __attribute__((ext_vector_type(4)));
typedef float f32x16 __attribute__((ext_vector_type(16)));
typedef unsigned short ushort_t;
typedef unsigned int uint;
typedef uint uint4v __attribute__((ext_vector_type(4)));

#define SEQ    2048
#define DMODEL 1024
#define NHEAD  16
#define DKH    64
#define NBATCH 2
#define MROWS  (NBATCH*SEQ)   // 4096
#define LOG2E  1.44269504088896340736f

__device__ __forceinline__ uint pk2(float a, float b) {
  bf16x2 t; t[0] = (__bf16)a; t[1] = (__bf16)b;
  return __builtin_bit_cast(uint, t);
}
__device__ __forceinline__ ushort_t b1(float a) {
  return __builtin_bit_cast(ushort_t, (__bf16)a);
}
__device__ __forceinline__ float fexp2(float x) {
#if __has_builtin(__builtin_amdgcn_exp2f)
  return __builtin_amdgcn_exp2f(x);
#else
  return exp2f(x);
#endif
}

__device__ __forceinline__ void gload16(const void* g, void* l) {
  __builtin_amdgcn_global_load_lds(
      (const __attribute__((address_space(1))) void*)g,
      (__attribute__((address_space(3))) void*)l, 16, 0, 0);
}

__device__ __forceinline__ f32x4 mfma16(bf16x8 a, bf16x8 b, f32x4 c) {
  return __builtin_amdgcn_mfma_f32_16x16x32_bf16(a, b, c, 0, 0, 0);
}
__device__ __forceinline__ f32x16 mfma32(bf16x8 a, bf16x8 b, f32x16 c) {
  return __builtin_amdgcn_mfma_f32_32x32x16_bf16(a, b, c, 0, 0, 0);
}

// ------- fused fp32 -> bf16 convert + RoPE cos/sin table (one launch) -----
__global__ __launch_bounds__(256) void cvt_all(
    const float* __restrict__ x, const float* __restrict__ wq,
    const float* __restrict__ wk, const float* __restrict__ wv,
    const float* __restrict__ wo, const int* __restrict__ tokpos,
    uint2* __restrict__ out, float2* __restrict__ tab)
{
  int b = blockIdx.x;
  if (b >= 8192) {                            // rope table (fp64 for accuracy)
    int t = (b - 8192) * 256 + threadIdx.x;   // [0, 65536)
    int s = t >> 5, k = t & 31;
    double inv = pow(10000.0, -(double)(2 * k) / 64.0);
    double ang = (double)tokpos[s] * inv;
    tab[t] = make_float2((float)cos(ang), (float)sin(ang));
    return;
  }
  const float4* src; uint2* dst; int i;
  if (b < 4096) {
    i = b * 256 + threadIdx.x; src = (const float4*)x; dst = out;
  } else {
    int s = (b - 4096) >> 10;
    i = ((b - 4096) & 1023) * 256 + threadIdx.x;
    src = (const float4*)(s == 0 ? wq : s == 1 ? wk : s == 2 ? wv : wo);
    dst = out + (size_t)1048576 + (size_t)s * 262144;
  }
  float4 v = src[i];
  uint2 r; r.x = pk2(v.x, v.y); r.y = pk2(v.z, v.w);
  dst[i] = r;
}

// ---------------- NT GEMM 128x128 tile, BK=64, 4 waves --------------------
// Counted-vmcnt 2-slot schedule (R13) + XCD swizzle (R14) — both verified.
__global__ __launch_bounds__(256) void gemm_nt(
    const ushort_t* __restrict__ A, const ushort_t* __restrict__ W,
    const float2* __restrict__ tab,
    ushort_t* __restrict__ Qo, ushort_t* __restrict__ Ko, ushort_t* __restrict__ Vo,
    float* __restrict__ outf, int fused, int nbx)
{
  __shared__ ushort_t lA[2][128 * 64];
  __shared__ ushort_t lB[2][128 * 64];
  const int tid = threadIdx.x;
  const int lin = blockIdx.y * nbx + blockIdx.x;
  const int nwg = nbx * gridDim.y;
  const int n = (lin & 7) * (nwg >> 3) + (lin >> 3);
  const int vbx = n % nbx, vby = n / nbx;
  const int w = tid >> 6, l = tid & 63, lo = l & 15, hi = l >> 4;
  const int wr = (w >> 1) * 64, wc = (w & 1) * 64;
  const char* Ab = (const char*)A + (size_t)vby * 128 * 2048;
  const char* Bb = (const char*)W + (size_t)vbx * 128 * 2048;
  f32x4 acc[4][4] = {};

  const int o0 = w * 1024 + l * 16;
  const int r0 = o0 >> 7;
  const int us = ((o0 >> 4) & 7) ^ (r0 & 7);
  const char* ap = Ab + (size_t)r0 * 2048 + us * 16;
  const char* bp = Bb + (size_t)r0 * 2048 + us * 16;

  auto stage = [&](char* dA, char* dB, const char* aq, const char* bq) {
    #pragma unroll
    for (int i = 0; i < 4; ++i) {           // rows r0 + 32*i
      gload16(aq + i * 65536, dA + w * 1024 + i * 4096);
      gload16(bq + i * 65536, dB + w * 1024 + i * 4096);
    }
  };
  auto comp = [&](const ushort_t* lAb, const ushort_t* lBb) {
    #pragma unroll
    for (int c = 0; c < 2; ++c) {
      bf16x8 af[4], wf[4];
      #pragma unroll
      for (int m = 0; m < 4; ++m) {
        int row = wr + m * 16 + lo;
        af[m] = *(const bf16x8*)((const char*)lAb + row * 128 + ((c * 64 + hi * 16) ^ ((row & 7) << 4)));
      }
      #pragma unroll
      for (int n2 = 0; n2 < 4; ++n2) {
        int row = wc + n2 * 16 + lo;
        wf[n2] = *(const bf16x8*)((const char*)lBb + row * 128 + ((c * 64 + hi * 16) ^ ((row & 7) << 4)));
      }
      #pragma unroll
      for (int m = 0; m < 4; ++m)
        #pragma unroll
        for (int n2 = 0; n2 < 4; ++n2)
          acc[m][n2] = mfma16(af[m], wf[n2], acc[m][n2]);
    }
  };

  stage((char*)lA[0], (char*)lB[0], ap, bp); ap += 128; bp += 128;   // step 0
  #pragma unroll 1
  for (int it = 0; it < 8; ++it) {
    stage((char*)lA[1], (char*)lB[1], ap, bp); ap += 128; bp += 128; // step 2it+1
    asm volatile("s_waitcnt vmcnt(8)" ::: "memory");   // slot-0 writes landed
    __builtin_amdgcn_s_barrier();                      // publish slot 0
    asm volatile("" ::: "memory");
    comp(lA[0], lB[0]);
    __builtin_amdgcn_s_barrier();                      // release slot 0
    asm volatile("" ::: "memory");
    if (it < 7) {
      stage((char*)lA[0], (char*)lB[0], ap, bp); ap += 128; bp += 128; // step 2it+2
      asm volatile("s_waitcnt vmcnt(8)" ::: "memory"); // slot-1 writes landed
    } else {
      asm volatile("s_waitcnt vmcnt(0)" ::: "memory");
    }
    __builtin_amdgcn_s_barrier();                      // publish slot 1
    asm volatile("" ::: "memory");
    comp(lA[1], lB[1]);
    __builtin_amdgcn_s_barrier();                      // release slot 1
    asm volatile("" ::: "memory");
  }

  const int mode = fused ? (vbx >> 3) : 3;
  const int colblk = fused ? (vbx & 7) : vbx;
  const int rowbase = vby * 128 + wr + hi * 4;
  const int colbase = colblk * 128 + wc + lo;

  if (mode == 3) {
    #pragma unroll
    for (int m = 0; m < 4; ++m)
      #pragma unroll
      for (int n2 = 0; n2 < 4; ++n2) {
        int e = colbase + n2 * 16;
        #pragma unroll
        for (int r = 0; r < 4; ++r) {
          int row = rowbase + m * 16 + r;
          outf[(size_t)row * 1024 + e] = acc[m][n2][r];
        }
      }
    return;
  }
  if (mode == 2) {
    // V^T store with key-column permutation (PV B-operand = raw P regs).
    #pragma unroll
    for (int m = 0; m < 4; ++m) {
      int row0 = rowbase + m * 16;
      int b = row0 >> 11, s = row0 & 2047;
      int b2 = (s >> 2) & 3;                               // 4-block index
      int sp = (s & ~12) | ((b2 & 1) << 3) | ((b2 >> 1) << 2);  // swap blks 1<->2
      #pragma unroll
      for (int n2 = 0; n2 < 4; ++n2) {
        int e = colbase + n2 * 16;
        int h = e >> 6, dk = e & 63;
        uint2 pk;
        pk.x = pk2(acc[m][n2][0], acc[m][n2][1]);
        pk.y = pk2(acc[m][n2][2], acc[m][n2][3]);
        *(uint2*)(Vo + ((size_t)((b * NHEAD + h) * DKH + dk) * SEQ + sp)) = pk;
      }
    }
    return;
  }
  ushort_t* outb = (mode == 0) ? Qo : Ko;
  const float qscale = (mode == 0) ? (0.125f * LOG2E) : 1.0f;
  #pragma unroll
  for (int m = 0; m < 4; ++m) {
    #pragma unroll
    for (int n2 = 0; n2 < 4; ++n2) {
      int e = colbase + n2 * 16;
      int h = e >> 6, dk = e & 63, kf = dk >> 1;
      float sgn = (e & 1) ? 1.0f : -1.0f;
      #pragma unroll
      for (int r = 0; r < 4; ++r) {
        int row = rowbase + m * 16 + r;
        int s = row & 2047, b = row >> 11;
        float2 cs = tab[s * 32 + kf];
        float v = acc[m][n2][r];
        float p = __shfl_xor(v, 1, 64);
        float res = (v * cs.x + sgn * p * cs.y) * qscale;
        outb[((size_t)((b * NHEAD + h) * SEQ + s)) * DKH + dk] = b1(res);
      }
    }
  }
}

// ---------------- flash attention fwd: front-loaded-read pipeline ---------
// R19: per step {vmcnt(0) [step-t stage landed, issued one compute earlier]
// -> ALL 8 ds_reads -> lgkmcnt(0) [reads returned = WAR fence] -> stage(t+1)
// -> pure-register compute}. Removes mid-compute LDS stalls; one LDS
// round-trip per step instead of per-group. Same bytes, same arithmetic.
__global__ __launch_bounds__(256) void attn_fwd(
    const ushort_t* __restrict__ Qg, const ushort_t* __restrict__ Kg,
    const ushort_t* __restrict__ VTg, ushort_t* __restrict__ attn)
{
  // main loop: wave w owns [w*16384, w*16384+16384): 2 slots of 8KB [K 4K|V 4K]
  // epilogue: accO dump 4 x 16KB at 0..65536, lsum at 65536 + w*512
  __shared__ char lds[67584];
  const int tid = threadIdx.x;                // 0..255
  const int w = tid >> 6, l = tid & 63;
  const int q31 = l & 31, hf = l >> 5, s7 = l & 7;
  // XCD swizzle (R14): 1024 blocks = 8 XCDs x 128; each XCD gets 4 heads.
  const int lin = blockIdx.y * gridDim.x + blockIdx.x;
  const int n = (lin & 7) * 128 + (lin >> 3);
  const int bh = n >> 5;                      // 0..31
  const int q0 = (n & 31) * 64;               // block's 64 queries
  const char* Kb = (const char*)Kg + (size_t)bh * 2048 * 128;   // key rows, 128B
  const char* Vb = (const char*)VTg + (size_t)bh * 64 * 4096;   // d rows, 4096B

  // Q fragments: qreg[qb][c] = Q[q0+qb*32+q31][c*16 + hf*8 .. +7]
  bf16x8 qreg[2][4];
  #pragma unroll
  for (int qb = 0; qb < 2; ++qb) {
    const ushort_t* qp = Qg + ((size_t)bh * 2048 + q0 + qb * 32 + q31) * 64 + hf * 8;
    #pragma unroll
    for (int c = 0; c < 4; ++c) qreg[qb][c] = *(const bf16x8*)(qp + c * 16);
  }

  f32x16 accO[2][2] = {};                     // [qb][db], partial over wave's keys
  float lsum[2] = {0.f, 0.f};

  // per-wave LDS read addresses (row l&31, swizzled 32B col chunks)
  char* wlds = lds + w * 16384;
  const char* ra[4];
  #pragma unroll
  for (int c = 0; c < 4; ++c)
    ra[c] = wlds + q31 * 128 + ((c * 32 + hf * 16) ^ (s7 << 4));

  // per-lane staging sources (pre-inverse-swizzled for linear LDS dest)
  const int usw = (l & 7) ^ (l >> 3);         // swizzled 16B slot for this lane
  const int kb0 = w * 512;                    // wave's key base
  const char* kst = Kb + (size_t)(kb0 + (l >> 3)) * 128 + usw * 16;          // += 4096/step
  const char* vst = Vb + (size_t)((l >> 3) + (usw >> 2) * 32) * 4096
                       + (size_t)kb0 * 2 + (usw & 3) * 16;                   // += 64/step

  auto stageT = [&](int slot) {               // 8 gload16/wave: K 4KB + V 4KB
    char* sp = wlds + slot;
    #pragma unroll
    for (int i = 0; i < 4; ++i)
      gload16(kst + i * 1024, sp + i * 1024 + l * 16);          // K rows +8i
    #pragma unroll
    for (int i = 0; i < 4; ++i)
      gload16(vst + i * 32768, sp + 4096 + i * 1024 + l * 16);  // V d-rows +8i
    kst += 4096; vst += 64;
  };

  stageT(0);                                  // step 0 -> slot 0
  #pragma unroll 2
  for (int t = 0; t < 16; ++t) {
    const int bo = (t & 1) * 8192;
    asm volatile("s_waitcnt vmcnt(0)" ::: "memory");    // step-t stage landed
    // ---- all LDS reads for this tile (front-loaded) ----
    bf16x8 kf[4], vA[2], vB[2];
    #pragma unroll
    for (int c = 0; c < 4; ++c)
      kf[c] = *(const bf16x8*)(ra[c] + bo);
    vA[0] = *(const bf16x8*)(ra[0] + bo + 4096);   // d 0..31,  kcl 0
    vB[0] = *(const bf16x8*)(ra[2] + bo + 4096);   // d 32..63, kcl 0
    vA[1] = *(const bf16x8*)(ra[1] + bo + 4096);   // d 0..31,  kcl 1
    vB[1] = *(const bf16x8*)(ra[3] + bo + 4096);   // d 32..63, kcl 1
    asm volatile("s_waitcnt lgkmcnt(0)" ::: "memory");  // reads returned (WAR)
    if (t < 15) stageT(((t + 1) & 1) * 8192);           // stage step t+1
    // ---- pure-register compute ----
    f32x16 s0 = {}, s1 = {};
    __builtin_amdgcn_s_setprio(1);
    #pragma unroll
    for (int c = 0; c < 4; ++c) {
      s0 = mfma32(kf[c], qreg[0][c], s0);
      s1 = mfma32(kf[c], qreg[1][c], s1);
    }
    __builtin_amdgcn_s_setprio(0);
    // p[r] <-> within-tile key (r&3) + 8*(r>>2) + 4*hf
    float p0[16], p1[16];
    float t0 = 0.f, t1 = 0.f;
    #pragma unroll
    for (int r = 0; r < 16; ++r) { p0[r] = fexp2(s0[r]); t0 += p0[r]; }
    #pragma unroll
    for (int r = 0; r < 16; ++r) { p1[r] = fexp2(s1[r]); t1 += p1[r]; }
    lsum[0] += t0; lsum[1] += t1;
    #pragma unroll
    for (int kcl = 0; kcl < 2; ++kcl) {
      const float* a0 = p0 + kcl * 8;
      const float* a1 = p1 + kcl * 8;
      uint4v u0 = { pk2(a0[0], a0[1]), pk2(a0[2], a0[3]),
                    pk2(a0[4], a0[5]), pk2(a0[6], a0[7]) };
      uint4v u1 = { pk2(a1[0], a1[1]), pk2(a1[2], a1[3]),
                    pk2(a1[4], a1[5]), pk2(a1[6], a1[7]) };
      bf16x8 pb0 = __builtin_bit_cast(bf16x8, u0);
      bf16x8 pb1 = __builtin_bit_cast(bf16x8, u1);
      __builtin_amdgcn_s_setprio(1);
      accO[0][0] = mfma32(vA[kcl], pb0, accO[0][0]);
      accO[0][1] = mfma32(vB[kcl], pb0, accO[0][1]);
      accO[1][0] = mfma32(vA[kcl], pb1, accO[1][0]);
      accO[1][1] = mfma32(vB[kcl], pb1, accO[1][1]);
      __builtin_amdgcn_s_setprio(0);
    }
  }

  // -------- combine the 4 key-quarter partials (linear) --------
  __syncthreads();                            // all waves done with slots
  #pragma unroll
  for (int qb = 0; qb < 2; ++qb)
    #pragma unroll
    for (int db = 0; db < 2; ++db)
      #pragma unroll
      for (int c2 = 0; c2 < 4; ++c2) {
        int j = qb * 8 + db * 4 + c2;
        f32x4 v = { accO[qb][db][c2 * 4 + 0], accO[qb][db][c2 * 4 + 1],
                    accO[qb][db][c2 * 4 + 2], accO[qb][db][c2 * 4 + 3] };
        *(f32x4*)(lds + w * 16384 + j * 1024 + l * 16) = v;
      }
  *(float2*)(lds + 65536 + w * 512 + l * 8) = make_float2(lsum[0], lsum[1]);
  __syncthreads();

  // wave w reduces j-chunks w*4..w*4+3 across all 4 wave partials
  float lt0 = 0.f, lt1 = 0.f;
  #pragma unroll
  for (int wp = 0; wp < 4; ++wp) {
    float2 lo = *(const float2*)(lds + 65536 + wp * 512 + l * 8);
    lt0 += lo.x; lt1 += lo.y;
  }
  lt0 += __shfl_xor(lt0, 32, 64);
  lt1 += __shfl_xor(lt1, 32, 64);
  float inv0 = 1.0f / lt0, inv1 = 1.0f / lt1;
  int b = bh >> 4, head = bh & 15;
  #pragma unroll
  for (int jj = 0; jj < 4; ++jj) {
    int j = w * 4 + jj;
    int qb = j >> 3, db = (j >> 2) & 1, c2 = j & 3;
    f32x4 v = {0.f, 0.f, 0.f, 0.f};
    #pragma unroll
    for (int wp = 0; wp < 4; ++wp) {
      f32x4 u = *(const f32x4*)(lds + wp * 16384 + j * 1024 + l * 16);
      v[0] += u[0]; v[1] += u[1]; v[2] += u[2]; v[3] += u[3];
    }
    float inv = qb ? inv1 : inv0;
    int d0 = db * 32 + c2 * 8 + hf * 4;
    ushort_t* op = attn + (size_t)(b * 2048 + q0 + qb * 32 + q31) * 1024 + head * 64;
    uint2 pk;
    pk.x = pk2(v[0] * inv, v[1] * inv);
    pk.y = pk2(v[2] * inv, v[3] * inv);
    *(uint2*)(op + d0) = pk;
  }
}

// ---------------- launch ----------------
extern "C" void kernel_launch(void* const* d_in, const int* in_sizes, int n_in,
                              void* d_out, int out_size, void* d_ws, size_t ws_size,
                              hipStream_t stream) {
  const float* x  = (const float*)d_in[0];
  const int* tok  = (const int*)d_in[1];
  const float* wq = (const float*)d_in[2];
  const float* wk = (const float*)d_in[3];
  const float* wv = (const float*)d_in[4];
  const float* wo = (const float*)d_in[5];
  float* out = (float*)d_out;
  char* ws = (char*)d_ws;

  size_t off = 0;
  float2* tab = (float2*)(ws + off); off += (size_t)SEQ * 32 * sizeof(float2);   // 512 KB
  ushort_t* xb  = (ushort_t*)(ws + off); off += (size_t)MROWS * DMODEL * 2;      // 8 MB
  ushort_t* wqkv = (ushort_t*)(ws + off); off += (size_t)3 * DMODEL * DMODEL * 2; // 6 MB
  ushort_t* wob = (ushort_t*)(ws + off); off += (size_t)DMODEL * DMODEL * 2;     // 2 MB
  ushort_t* Qg  = (ushort_t*)(ws + off); off += (size_t)MROWS * DMODEL * 2;      // 8 MB
  ushort_t* Kg  = (ushort_t*)(ws + off); off += (size_t)MROWS * DMODEL * 2;      // 8 MB
  ushort_t* VTg = (ushort_t*)(ws + off); off += (size_t)MROWS * DMODEL * 2;      // 8 MB
  ushort_t* attnb = xb;  // alias: xb dead after projection GEMM
  if (ws_size < off) return;

  cvt_all<<<8448, 256, 0, stream>>>(x, wq, wk, wv, wo, tok, (uint2*)xb, tab);

  gemm_nt<<<dim3(24, 32), 256, 0, stream>>>(xb, wqkv, tab, Qg, Kg, VTg, nullptr, 1, 24);

  attn_fwd<<<dim3(SEQ / 64, NBATCH * NHEAD), 256, 0, stream>>>(Qg, Kg, VTg, attnb);

  gemm_nt<<<dim3(8, 32), 256, 0, stream>>>(attnb, wob, nullptr, nullptr, nullptr, nullptr, out, 0, 8);
}

// Round 20
// 118.068 us; speedup vs baseline: 1.3811x; 1.0117x over previous
//
#include <hip/hip_runtime.h>
#include <stdint.h>

typedef __bf16 bf16x8 __attribute__((ext_vector_type(8)));
typedef __bf16 bf16x2 __attribute__((ext_vector_type(2)));
typedef float f32x4 __attribute__((ext_vector_type(4)));
typedef float f32x16 __attribute__((ext_vector_type(16)));
typedef unsigned short ushort_t;
typedef unsigned int uint;
typedef uint uint4v __attribute__((ext_vector_type(4)));

#define SEQ    2048
#define DMODEL 1024
#define NHEAD  16
#define DKH    64
#define NBATCH 2
#define MROWS  (NBATCH*SEQ)   // 4096
#define LOG2E  1.44269504088896340736f

__device__ __forceinline__ uint pk2(float a, float b) {
  bf16x2 t; t[0] = (__bf16)a; t[1] = (__bf16)b;
  return __builtin_bit_cast(uint, t);
}
__device__ __forceinline__ ushort_t b1(float a) {
  return __builtin_bit_cast(ushort_t, (__bf16)a);
}
__device__ __forceinline__ float fexp2(float x) {
#if __has_builtin(__builtin_amdgcn_exp2f)
  return __builtin_amdgcn_exp2f(x);
#else
  return exp2f(x);
#endif
}

__device__ __forceinline__ void gload16(const void* g, void* l) {
  __builtin_amdgcn_global_load_lds(
      (const __attribute__((address_space(1))) void*)g,
      (__attribute__((address_space(3))) void*)l, 16, 0, 0);
}

__device__ __forceinline__ f32x4 mfma16(bf16x8 a, bf16x8 b, f32x4 c) {
  return __builtin_amdgcn_mfma_f32_16x16x32_bf16(a, b, c, 0, 0, 0);
}
__device__ __forceinline__ f32x16 mfma32(bf16x8 a, bf16x8 b, f32x16 c) {
  return __builtin_amdgcn_mfma_f32_32x32x16_bf16(a, b, c, 0, 0, 0);
}

#define BARRIER() do { __builtin_amdgcn_s_barrier(); asm volatile("" ::: "memory"); } while (0)

// ------- fused fp32 -> bf16 convert + RoPE cos/sin table (one launch) -----
__global__ __launch_bounds__(256) void cvt_all(
    const float* __restrict__ x, const float* __restrict__ wq,
    const float* __restrict__ wk, const float* __restrict__ wv,
    const float* __restrict__ wo, const int* __restrict__ tokpos,
    uint2* __restrict__ out, float2* __restrict__ tab)
{
  int b = blockIdx.x;
  if (b >= 8192) {                            // rope table (fp64 for accuracy)
    int t = (b - 8192) * 256 + threadIdx.x;   // [0, 65536)
    int s = t >> 5, k = t & 31;
    double inv = pow(10000.0, -(double)(2 * k) / 64.0);
    double ang = (double)tokpos[s] * inv;
    tab[t] = make_float2((float)cos(ang), (float)sin(ang));
    return;
  }
  const float4* src; uint2* dst; int i;
  if (b < 4096) {
    i = b * 256 + threadIdx.x; src = (const float4*)x; dst = out;
  } else {
    int s = (b - 4096) >> 10;
    i = ((b - 4096) & 1023) * 256 + threadIdx.x;
    src = (const float4*)(s == 0 ? wq : s == 1 ? wk : s == 2 ? wv : wo);
    dst = out + (size_t)1048576 + (size_t)s * 262144;
  }
  float4 v = src[i];
  uint2 r; r.x = pk2(v.x, v.y); r.y = pk2(v.z, v.w);
  dst[i] = r;
}

// ======== QKV GEMM: 256x256 tile, BK=64, 8 waves, 8-phase counted-vmcnt ====
// Template per T2+T3+T4+T5: per K-tile 4 phases, each {ds-reads | stage one
// 16KB half-tile | barrier | MFMA quadrant (setprio) | barrier}; vmcnt(4)
// once per tile. Stage ledger: A(t+1)@ph0/1 -> buf^1 (not read by tile t);
// B(t+2)@ph2/3 -> buf b AFTER B(t) fully read (ph1 barrier). Outstanding at
// tile end = A(t+1)[4] + B(t+2)[4]; vmcnt(4) lands A(t+1). Accumulation
// order per element identical to the 128^2 kernel -> bitwise-same outputs.
__global__ __launch_bounds__(512, 1) void gemm_qkv(
    const ushort_t* __restrict__ A, const ushort_t* __restrict__ W,
    const float2* __restrict__ tab,
    ushort_t* __restrict__ Qo, ushort_t* __restrict__ Ko, ushort_t* __restrict__ Vo)
{
  // [buf0: A 32K | B 32K][buf1: A 32K | B 32K]; rows 128B, XOR-swizzled
  __shared__ char lds[131072];
  const int tid = threadIdx.x;                // 0..511
  const int w = tid >> 6, l = tid & 63;
  const int wm = w >> 2, wn = w & 3;          // wave grid 2(M) x 4(N)
  const int lo = l & 15, hi = l >> 4;
  // XCD swizzle: 192 blocks = 8 XCDs x 24 (bijective)
  const int lin = blockIdx.y * 12 + blockIdx.x;
  const int vn = (lin & 7) * 24 + (lin >> 3);
  const int vbx = vn % 12, vby = vn / 12;
  const char* Ab = (const char*)A + (size_t)vby * 256 * 2048;
  const char* Bb = (const char*)W + (size_t)vbx * 256 * 2048;

  // per-thread staging source (pre-inverse-swizzled, linear LDS dest)
  // pass p: rows sr + 64p (src +p*131072, dst +p*8192); half h: src +h*262144
  const int sr = tid >> 3;
  const int us = (tid & 7) ^ (sr & 7);
  const char* aSrc = Ab + (size_t)sr * 2048 + us * 16;
  const char* bSrc = Bb + (size_t)sr * 2048 + us * 16;

  f32x4 acc[8][4] = {};

  auto stg = [&](char* dst, const char* src) {   // one 16KB half-tile
    gload16(src,          dst + tid * 16);
    gload16(src + 131072, dst + 8192 + tid * 16);
  };

  // prologue: A(0)h0,h1; B(0)h0,h1; B(1)h0,h1  (12 loads/thread)
  stg(lds,                 aSrc);
  stg(lds + 16384,         aSrc + 262144);
  stg(lds + 32768,         bSrc);
  stg(lds + 49152,         bSrc + 262144);
  stg(lds + 98304,         bSrc + 128);
  stg(lds + 114688,        bSrc + 128 + 262144);
  asm volatile("s_waitcnt vmcnt(4)" ::: "memory");  // A(0),B(0) landed
  BARRIER();

  #pragma unroll 1
  for (int t = 0; t < 16; ++t) {
    const int b = t & 1;
    const char* lA = lds + b * 65536;
    const char* lB = lA + 32768;
    char* nA = lds + (b ^ 1) * 65536;         // A(t+1) dest (other buf)
    char* nB = (char*)lB;                     // B(t+2) dest (same buf)
    bf16x8 af[4][2], wf[4][2];

    // ---- ph0: read af(rows 0..63 of wave) + wf[0..1]; stage A(t+1) h0 ----
    #pragma unroll
    for (int m = 0; m < 4; ++m) {
      int row = wm * 128 + m * 16 + lo;
      const char* base = lA + row * 128;
      int sw = (row & 7) << 4;
      af[m][0] = *(const bf16x8*)(base + ((hi * 16) ^ sw));
      af[m][1] = *(const bf16x8*)(base + ((64 + hi * 16) ^ sw));
    }
    #pragma unroll
    for (int j = 0; j < 2; ++j) {
      int row = wn * 64 + j * 16 + lo;
      const char* base = lB + row * 128;
      int sw = (row & 7) << 4;
      wf[j][0] = *(const bf16x8*)(base + ((hi * 16) ^ sw));
      wf[j][1] = *(const bf16x8*)(base + ((64 + hi * 16) ^ sw));
    }
    if (t < 15) stg(nA, aSrc + (t + 1) * 128);
    BARRIER();
    __builtin_amdgcn_s_setprio(1);
    #pragma unroll
    for (int m = 0; m < 4; ++m)
      #pragma unroll
      for (int n2 = 0; n2 < 2; ++n2) {
        acc[m][n2] = mfma16(af[m][0], wf[n2][0], acc[m][n2]);
        acc[m][n2] = mfma16(af[m][1], wf[n2][1], acc[m][n2]);
      }
    __builtin_amdgcn_s_setprio(0);
    BARRIER();

    // ---- ph1: read wf[2..3]; stage A(t+1) h1 ----
    #pragma unroll
    for (int j = 2; j < 4; ++j) {
      int row = wn * 64 + j * 16 + lo;
      const char* base = lB + row * 128;
      int sw = (row & 7) << 4;
      wf[j][0] = *(const bf16x8*)(base + ((hi * 16) ^ sw));
      wf[j][1] = *(const bf16x8*)(base + ((64 + hi * 16) ^ sw));
    }
    if (t < 15) stg(nA + 16384, aSrc + (t + 1) * 128 + 262144);
    BARRIER();
    __builtin_amdgcn_s_setprio(1);
    #pragma unroll
    for (int m = 0; m < 4; ++m)
      #pragma unroll
      for (int n2 = 2; n2 < 4; ++n2) {
        acc[m][n2] = mfma16(af[m][0], wf[n2][0], acc[m][n2]);
        acc[m][n2] = mfma16(af[m][1], wf[n2][1], acc[m][n2]);
      }
    __builtin_amdgcn_s_setprio(0);
    BARRIER();

    // ---- ph2: read af(rows 64..127 of wave); stage B(t+2) h0 ----
    #pragma unroll
    for (int m = 0; m < 4; ++m) {
      int row = wm * 128 + 64 + m * 16 + lo;
      const char* base = lA + row * 128;
      int sw = (row & 7) << 4;
      af[m][0] = *(const bf16x8*)(base + ((hi * 16) ^ sw));
      af[m][1] = *(const bf16x8*)(base + ((64 + hi * 16) ^ sw));
    }
    if (t < 14) stg(nB, bSrc + (t + 2) * 128);
    BARRIER();
    __builtin_amdgcn_s_setprio(1);
    #pragma unroll
    for (int m = 0; m < 4; ++m)
      #pragma unroll
      for (int n2 = 0; n2 < 2; ++n2) {
        acc[4 + m][n2] = mfma16(af[m][0], wf[n2][0], acc[4 + m][n2]);
        acc[4 + m][n2] = mfma16(af[m][1], wf[n2][1], acc[4 + m][n2]);
      }
    __builtin_amdgcn_s_setprio(0);
    BARRIER();

    // ---- ph3: stage B(t+2) h1; tile-end counted vmcnt ----
    if (t < 14) stg(nB + 16384, bSrc + (t + 2) * 128 + 262144);
    BARRIER();
    __builtin_amdgcn_s_setprio(1);
    #pragma unroll
    for (int m = 0; m < 4; ++m)
      #pragma unroll
      for (int n2 = 2; n2 < 4; ++n2) {
        acc[4 + m][n2] = mfma16(af[m][0], wf[n2][0], acc[4 + m][n2]);
        acc[4 + m][n2] = mfma16(af[m][1], wf[n2][1], acc[4 + m][n2]);
      }
    __builtin_amdgcn_s_setprio(0);
    if (t < 14)       asm volatile("s_waitcnt vmcnt(4)" ::: "memory");
    else if (t == 14) asm volatile("s_waitcnt vmcnt(0)" ::: "memory");
    BARRIER();
  }

  // ---- epilogues (same math/layouts as the verified 128^2 kernel) ----
  const int mode = vbx >> 2;                   // 0 Q, 1 K, 2 V
  const int colbase = (vbx & 3) * 256 + wn * 64 + lo;
  const int rowb0 = vby * 256 + wm * 128 + hi * 4;

  if (mode == 2) {
    // V^T store with key-column permutation (PV B-operand = raw P regs)
    #pragma unroll
    for (int i = 0; i < 8; ++i) {
      int row0 = rowb0 + i * 16;
      int bb = row0 >> 11, s = row0 & 2047;
      int b2 = (s >> 2) & 3;
      int sp = (s & ~12) | ((b2 & 1) << 3) | ((b2 >> 1) << 2);
      #pragma unroll
      for (int n2 = 0; n2 < 4; ++n2) {
        int e = colbase + n2 * 16;
        int h = e >> 6, dk = e & 63;
        uint2 pk;
        pk.x = pk2(acc[i][n2][0], acc[i][n2][1]);
        pk.y = pk2(acc[i][n2][2], acc[i][n2][3]);
        *(uint2*)(Vo + ((size_t)((bb * NHEAD + h) * DKH + dk) * SEQ + sp)) = pk;
      }
    }
    return;
  }
  ushort_t* outb = (mode == 0) ? Qo : Ko;
  const float qscale = (mode == 0) ? (0.125f * LOG2E) : 1.0f;
  #pragma unroll
  for (int i = 0; i < 8; ++i) {
    #pragma unroll
    for (int n2 = 0; n2 < 4; ++n2) {
      int e = colbase + n2 * 16;
      int h = e >> 6, dk = e & 63, kf = dk >> 1;
      float sgn = (e & 1) ? 1.0f : -1.0f;
      #pragma unroll
      for (int r = 0; r < 4; ++r) {
        int row = rowb0 + i * 16 + r;
        int s = row & 2047, bb = row >> 11;
        float2 cs = tab[s * 32 + kf];
        float v = acc[i][n2][r];
        float p = __shfl_xor(v, 1, 64);
        float res = (v * cs.x + sgn * p * cs.y) * qscale;
        outb[((size_t)((bb * NHEAD + h) * SEQ + s)) * DKH + dk] = b1(res);
      }
    }
  }
}

// ---------------- NT GEMM 128x128 tile (WO only) --------------------------
// Counted-vmcnt 2-slot schedule (R13) + XCD swizzle (R14) — both verified.
__global__ __launch_bounds__(256) void gemm_nt(
    const ushort_t* __restrict__ A, const ushort_t* __restrict__ W,
    float* __restrict__ outf, int nbx)
{
  __shared__ ushort_t lA[2][128 * 64];
  __shared__ ushort_t lB[2][128 * 64];
  const int tid = threadIdx.x;
  const int lin = blockIdx.y * nbx + blockIdx.x;
  const int nwg = nbx * gridDim.y;
  const int n = (lin & 7) * (nwg >> 3) + (lin >> 3);
  const int vbx = n % nbx, vby = n / nbx;
  const int w = tid >> 6, l = tid & 63, lo = l & 15, hi = l >> 4;
  const int wr = (w >> 1) * 64, wc = (w & 1) * 64;
  const char* Ab = (const char*)A + (size_t)vby * 128 * 2048;
  const char* Bb = (const char*)W + (size_t)vbx * 128 * 2048;
  f32x4 acc[4][4] = {};

  const int o0 = w * 1024 + l * 16;
  const int r0 = o0 >> 7;
  const int us = ((o0 >> 4) & 7) ^ (r0 & 7);
  const char* ap = Ab + (size_t)r0 * 2048 + us * 16;
  const char* bp = Bb + (size_t)r0 * 2048 + us * 16;

  auto stage = [&](char* dA, char* dB, const char* aq, const char* bq) {
    #pragma unroll
    for (int i = 0; i < 4; ++i) {           // rows r0 + 32*i
      gload16(aq + i * 65536, dA + w * 1024 + i * 4096);
      gload16(bq + i * 65536, dB + w * 1024 + i * 4096);
    }
  };
  auto comp = [&](const ushort_t* lAb, const ushort_t* lBb) {
    #pragma unroll
    for (int c = 0; c < 2; ++c) {
      bf16x8 af[4], wf[4];
      #pragma unroll
      for (int m = 0; m < 4; ++m) {
        int row = wr + m * 16 + lo;
        af[m] = *(const bf16x8*)((const char*)lAb + row * 128 + ((c * 64 + hi * 16) ^ ((row & 7) << 4)));
      }
      #pragma unroll
      for (int n2 = 0; n2 < 4; ++n2) {
        int row = wc + n2 * 16 + lo;
        wf[n2] = *(const bf16x8*)((const char*)lBb + row * 128 + ((c * 64 + hi * 16) ^ ((row & 7) << 4)));
      }
      #pragma unroll
      for (int m = 0; m < 4; ++m)
        #pragma unroll
        for (int n2 = 0; n2 < 4; ++n2)
          acc[m][n2] = mfma16(af[m], wf[n2], acc[m][n2]);
    }
  };

  stage((char*)lA[0], (char*)lB[0], ap, bp); ap += 128; bp += 128;   // step 0
  #pragma unroll 1
  for (int it = 0; it < 8; ++it) {
    stage((char*)lA[1], (char*)lB[1], ap, bp); ap += 128; bp += 128; // step 2it+1
    asm volatile("s_waitcnt vmcnt(8)" ::: "memory");   // slot-0 writes landed
    BARRIER();
    comp(lA[0], lB[0]);
    BARRIER();
    if (it < 7) {
      stage((char*)lA[0], (char*)lB[0], ap, bp); ap += 128; bp += 128; // step 2it+2
      asm volatile("s_waitcnt vmcnt(8)" ::: "memory"); // slot-1 writes landed
    } else {
      asm volatile("s_waitcnt vmcnt(0)" ::: "memory");
    }
    BARRIER();
    comp(lA[1], lB[1]);
    BARRIER();
  }

  const int rowbase = vby * 128 + wr + hi * 4;
  const int colbase = vbx * 128 + wc + lo;
  #pragma unroll
  for (int m = 0; m < 4; ++m)
    #pragma unroll
    for (int n2 = 0; n2 < 4; ++n2) {
      int e = colbase + n2 * 16;
      #pragma unroll
      for (int r = 0; r < 4; ++r) {
        int row = rowbase + m * 16 + r;
        outf[(size_t)row * 1024 + e] = acc[m][n2][r];
      }
    }
}

// ---------------- flash attention fwd: front-loaded-read pipeline ---------
// (R19 — verified 54.0us / absmax 1.46e-3.)
__global__ __launch_bounds__(256) void attn_fwd(
    const ushort_t* __restrict__ Qg, const ushort_t* __restrict__ Kg,
    const ushort_t* __restrict__ VTg, ushort_t* __restrict__ attn)
{
  __shared__ char lds[67584];
  const int tid = threadIdx.x;                // 0..255
  const int w = tid >> 6, l = tid & 63;
  const int q31 = l & 31, hf = l >> 5, s7 = l & 7;
  const int lin = blockIdx.y * gridDim.x + blockIdx.x;
  const int n = (lin & 7) * 128 + (lin >> 3);
  const int bh = n >> 5;                      // 0..31
  const int q0 = (n & 31) * 64;               // block's 64 queries
  const char* Kb = (const char*)Kg + (size_t)bh * 2048 * 128;   // key rows, 128B
  const char* Vb = (const char*)VTg + (size_t)bh * 64 * 4096;   // d rows, 4096B

  bf16x8 qreg[2][4];
  #pragma unroll
  for (int qb = 0; qb < 2; ++qb) {
    const ushort_t* qp = Qg + ((size_t)bh * 2048 + q0 + qb * 32 + q31) * 64 + hf * 8;
    #pragma unroll
    for (int c = 0; c < 4; ++c) qreg[qb][c] = *(const bf16x8*)(qp + c * 16);
  }

  f32x16 accO[2][2] = {};
  float lsum[2] = {0.f, 0.f};

  char* wlds = lds + w * 16384;
  const char* ra[4];
  #pragma unroll
  for (int c = 0; c < 4; ++c)
    ra[c] = wlds + q31 * 128 + ((c * 32 + hf * 16) ^ (s7 << 4));

  const int usw = (l & 7) ^ (l >> 3);
  const int kb0 = w * 512;
  const char* kst = Kb + (size_t)(kb0 + (l >> 3)) * 128 + usw * 16;
  const char* vst = Vb + (size_t)((l >> 3) + (usw >> 2) * 32) * 4096
                       + (size_t)kb0 * 2 + (usw & 3) * 16;

  auto stageT = [&](int slot) {
    char* sp = wlds + slot;
    #pragma unroll
    for (int i = 0; i < 4; ++i)
      gload16(kst + i * 1024, sp + i * 1024 + l * 16);
    #pragma unroll
    for (int i = 0; i < 4; ++i)
      gload16(vst + i * 32768, sp + 4096 + i * 1024 + l * 16);
    kst += 4096; vst += 64;
  };

  stageT(0);
  #pragma unroll 2
  for (int t = 0; t < 16; ++t) {
    const int bo = (t & 1) * 8192;
    asm volatile("s_waitcnt vmcnt(0)" ::: "memory");
    bf16x8 kf[4], vA[2], vB[2];
    #pragma unroll
    for (int c = 0; c < 4; ++c)
      kf[c] = *(const bf16x8*)(ra[c] + bo);
    vA[0] = *(const bf16x8*)(ra[0] + bo + 4096);
    vB[0] = *(const bf16x8*)(ra[2] + bo + 4096);
    vA[1] = *(const bf16x8*)(ra[1] + bo + 4096);
    vB[1] = *(const bf16x8*)(ra[3] + bo + 4096);
    asm volatile("s_waitcnt lgkmcnt(0)" ::: "memory");
    if (t < 15) stageT(((t + 1) & 1) * 8192);
    f32x16 s0 = {}, s1 = {};
    __builtin_amdgcn_s_setprio(1);
    #pragma unroll
    for (int c = 0; c < 4; ++c) {
      s0 = mfma32(kf[c], qreg[0][c], s0);
      s1 = mfma32(kf[c], qreg[1][c], s1);
    }
    __builtin_amdgcn_s_setprio(0);
    float p0[16], p1[16];
    float t0 = 0.f, t1 = 0.f;
    #pragma unroll
    for (int r = 0; r < 16; ++r) { p0[r] = fexp2(s0[r]); t0 += p0[r]; }
    #pragma unroll
    for (int r = 0; r < 16; ++r) { p1[r] = fexp2(s1[r]); t1 += p1[r]; }
    lsum[0] += t0; lsum[1] += t1;
    #pragma unroll
    for (int kcl = 0; kcl < 2; ++kcl) {
      const float* a0 = p0 + kcl * 8;
      const float* a1 = p1 + kcl * 8;
      uint4v u0 = { pk2(a0[0], a0[1]), pk2(a0[2], a0[3]),
                    pk2(a0[4], a0[5]), pk2(a0[6], a0[7]) };
      uint4v u1 = { pk2(a1[0], a1[1]), pk2(a1[2], a1[3]),
                    pk2(a1[4], a1[5]), pk2(a1[6], a1[7]) };
      bf16x8 pb0 = __builtin_bit_cast(bf16x8, u0);
      bf16x8 pb1 = __builtin_bit_cast(bf16x8, u1);
      __builtin_amdgcn_s_setprio(1);
      accO[0][0] = mfma32(vA[kcl], pb0, accO[0][0]);
      accO[0][1] = mfma32(vB[kcl], pb0, accO[0][1]);
      accO[1][0] = mfma32(vA[kcl], pb1, accO[1][0]);
      accO[1][1] = mfma32(vB[kcl], pb1, accO[1][1]);
      __builtin_amdgcn_s_setprio(0);
    }
  }

  __syncthreads();
  #pragma unroll
  for (int qb = 0; qb < 2; ++qb)
    #pragma unroll
    for (int db = 0; db < 2; ++db)
      #pragma unroll
      for (int c2 = 0; c2 < 4; ++c2) {
        int j = qb * 8 + db * 4 + c2;
        f32x4 v = { accO[qb][db][c2 * 4 + 0], accO[qb][db][c2 * 4 + 1],
                    accO[qb][db][c2 * 4 + 2], accO[qb][db][c2 * 4 + 3] };
        *(f32x4*)(lds + w * 16384 + j * 1024 + l * 16) = v;
      }
  *(float2*)(lds + 65536 + w * 512 + l * 8) = make_float2(lsum[0], lsum[1]);
  __syncthreads();

  float lt0 = 0.f, lt1 = 0.f;
  #pragma unroll
  for (int wp = 0; wp < 4; ++wp) {
    float2 lo2 = *(const float2*)(lds + 65536 + wp * 512 + l * 8);
    lt0 += lo2.x; lt1 += lo2.y;
  }
  lt0 += __shfl_xor(lt0, 32, 64);
  lt1 += __shfl_xor(lt1, 32, 64);
  float inv0 = 1.0f / lt0, inv1 = 1.0f / lt1;
  int b = bh >> 4, head = bh & 15;
  #pragma unroll
  for (int jj = 0; jj < 4; ++jj) {
    int j = w * 4 + jj;
    int qb = j >> 3, db = (j >> 2) & 1, c2 = j & 3;
    f32x4 v = {0.f, 0.f, 0.f, 0.f};
    #pragma unroll
    for (int wp = 0; wp < 4; ++wp) {
      f32x4 u = *(const f32x4*)(lds + wp * 16384 + j * 1024 + l * 16);
      v[0] += u[0]; v[1] += u[1]; v[2] += u[2]; v[3] += u[3];
    }
    float inv = qb ? inv1 : inv0;
    int d0 = db * 32 + c2 * 8 + hf * 4;
    ushort_t* op = attn + (size_t)(b * 2048 + q0 + qb * 32 + q31) * 1024 + head * 64;
    uint2 pk;
    pk.x = pk2(v[0] * inv, v[1] * inv);
    pk.y = pk2(v[2] * inv, v[3] * inv);
    *(uint2*)(op + d0) = pk;
  }
}

// ---------------- launch ----------------
extern "C" void kernel_launch(void* const* d_in, const int* in_sizes, int n_in,
                              void* d_out, int out_size, void* d_ws, size_t ws_size,
                              hipStream_t stream) {
  const float* x  = (const float*)d_in[0];
  const int* tok  = (const int*)d_in[1];
  const float* wq = (const float*)d_in[2];
  const float* wk = (const float*)d_in[3];
  const float* wv = (const float*)d_in[4];
  const float* wo = (const float*)d_in[5];
  float* out = (float*)d_out;
  char* ws = (char*)d_ws;

  size_t off = 0;
  float2* tab = (float2*)(ws + off); off += (size_t)SEQ * 32 * sizeof(float2);   // 512 KB
  ushort_t* xb  = (ushort_t*)(ws + off); off += (size_t)MROWS * DMODEL * 2;      // 8 MB
  ushort_t* wqkv = (ushort_t*)(ws + off); off += (size_t)3 * DMODEL * DMODEL * 2; // 6 MB
  ushort_t* wob = (ushort_t*)(ws + off); off += (size_t)DMODEL * DMODEL * 2;     // 2 MB
  ushort_t* Qg  = (ushort_t*)(ws + off); off += (size_t)MROWS * DMODEL * 2;      // 8 MB
  ushort_t* Kg  = (ushort_t*)(ws + off); off += (size_t)MROWS * DMODEL * 2;      // 8 MB
  ushort_t* VTg = (ushort_t*)(ws + off); off += (size_t)MROWS * DMODEL * 2;      // 8 MB
  ushort_t* attnb = xb;  // alias: xb dead after projection GEMM
  if (ws_size < off) return;

  cvt_all<<<8448, 256, 0, stream>>>(x, wq, wk, wv, wo, tok, (uint2*)xb, tab);

  gemm_qkv<<<dim3(12, 16), 512, 0, stream>>>(xb, wqkv, tab, Qg, Kg, VTg);

  attn_fwd<<<dim3(SEQ / 64, NBATCH * NHEAD), 256, 0, stream>>>(Qg, Kg, VTg, attnb);

  gemm_nt<<<dim3(8, 32), 256, 0, stream>>>(attnb, wob, out, 8);
}